// Round 12
// baseline (620.000 us; speedup 1.0000x reference)
//
#include <hip/hip_runtime.h>

typedef unsigned int uint;
typedef unsigned short ushort;
typedef __attribute__((ext_vector_type(8))) short bf16x8;
typedef __attribute__((ext_vector_type(4))) float f32x4;
typedef __attribute__((ext_vector_type(2))) _Float16 half2_t;

#define NN 50000
#define NE 800000
#define NG 64
#define NODE_F 11
#define EDGE_F 14
#define HD 128
#define NL 3
#define BN_EPS 1e-5f

#if defined(__has_builtin)
#if __has_builtin(__builtin_amdgcn_fdot2)
#define HAS_DOT2 1
#endif
#endif

__device__ __forceinline__ uint bfround(float v) {
    uint b = __float_as_uint(v);
    return (b + 0x7fffu + ((b >> 16) & 1u)) >> 16;
}

__device__ __forceinline__ float dot2f(half2_t a, half2_t b, float acc) {
#ifdef HAS_DOT2
    return __builtin_amdgcn_fdot2(a, b, acc, false);
#else
    return acc + (float)a[0] * (float)b[0] + (float)a[1] * (float)b[1];
#endif
}

__device__ __forceinline__ half2_t u2h2(uint u) {
    return __builtin_bit_cast(half2_t, u);
}

// --- init: weights prep (blocks<448) + node embed->hbA (middle) + ea f16 permute (rest)
__global__ __launch_bounds__(256)
void init_kernel(const float* __restrict__ x, const float* __restrict__ nW,
                 const float* __restrict__ nb_, const float* __restrict__ lin1,
                 const float* __restrict__ lin2, const float* __restrict__ proj,
                 const float* __restrict__ ea, const int* __restrict__ eid,
                 uint* __restrict__ hb, uint* __restrict__ ea_h,
                 ushort* __restrict__ wb, float* __restrict__ projT)
{
    int bid = blockIdx.x;
    if (bid < 448) {
        int idx = bid * 256 + threadIdx.x;
        if (idx < 6 * HD * HD) {
            int m = idx >> 14, e = idx & (HD * HD - 1);
            const float* src = (m < 3) ? (lin1 + m * HD * HD) : (lin2 + (m - 3) * HD * HD);
            wb[idx] = (ushort)bfround(src[e]);
        } else if (idx < 7 * HD * HD) {
            int e = idx - 6 * HD * HD;
            int r = e >> 7, c = e & 127;
            projT[c * HD + r] = proj[r * HD + c];
        }
    } else if (bid < 448 + 12500) {
        int idx = (bid - 448) * 256 + threadIdx.x;
        int node = idx >> 6, cp = idx & 63;
        int c2 = cp * 2;
        const float* xr = x + node * NODE_F;
        const float* w0 = nW + c2 * NODE_F;
        const float* w1 = w0 + NODE_F;
        float a0 = nb_[c2], a1 = nb_[c2 + 1];
#pragma unroll
        for (int f = 0; f < NODE_F; ++f) { float xv = xr[f]; a0 += xv * w0[f]; a1 += xv * w1[f]; }
        hb[idx] = bfround(a0) | (bfround(a1) << 16);
    } else {
        int idx = (bid - 448 - 12500) * 256 + threadIdx.x;
        int el = idx >> 3, f2 = idx & 7;
        if (f2 >= 7) return;
        float2 v = *(const float2*)(ea + (size_t)eid[el] * EDGE_F + 2 * f2);
        half2_t hh;
        hh[0] = (_Float16)v.x;
        hh[1] = (_Float16)v.y;
        ea_h[(size_t)el * 7 + f2] = __builtin_bit_cast(uint, hh);
    }
}

// ----------------------------- CSR construction ----------------------------
__global__ __launch_bounds__(256)
void hist_kernel(const int* __restrict__ ei, int* __restrict__ deg)
{
    int e = blockIdx.x * 256 + threadIdx.x;
    if (e < NE) atomicAdd(&deg[ei[NE + e]], 1);
}

__global__ __launch_bounds__(256)
void scan1_kernel(const int* __restrict__ deg, int* __restrict__ incl, int* __restrict__ bsum)
{
    int i = blockIdx.x * 256 + threadIdx.x;
    int v = (i < NN) ? deg[i] : 0;
    int lane = threadIdx.x & 63;
#pragma unroll
    for (int off = 1; off < 64; off <<= 1) {
        int u = __shfl_up(v, off);
        if (lane >= off) v += u;
    }
    __shared__ int wsum[4];
    if (lane == 63) wsum[threadIdx.x >> 6] = v;
    __syncthreads();
    int wid = threadIdx.x >> 6;
    int add = 0;
#pragma unroll
    for (int w = 0; w < 3; ++w) if (w < wid) add += wsum[w];
    v += add;
    if (i < NN) incl[i] = v;
    if (threadIdx.x == 255) bsum[blockIdx.x] = v;
}

__global__ __launch_bounds__(256)
void scan2_kernel(const int* __restrict__ bsum, int* __restrict__ bscan, int nb)
{
    int i = threadIdx.x;
    int v = (i < nb) ? bsum[i] : 0;
    int lane = i & 63;
#pragma unroll
    for (int off = 1; off < 64; off <<= 1) {
        int u = __shfl_up(v, off);
        if (lane >= off) v += u;
    }
    __shared__ int wsum[4];
    if (lane == 63) wsum[i >> 6] = v;
    __syncthreads();
    int wid = i >> 6;
    int add = 0;
#pragma unroll
    for (int w = 0; w < 3; ++w) if (w < wid) add += wsum[w];
    v += add;
    bscan[i] = v;
}

__global__ __launch_bounds__(256)
void scan3_kernel(const int* __restrict__ deg, const int* __restrict__ incl,
                  const int* __restrict__ bscan, int* __restrict__ row_start,
                  int* __restrict__ cursor)
{
    int i = blockIdx.x * 256 + threadIdx.x;
    if (i >= NN) return;
    int b = blockIdx.x;
    int base = (b > 0) ? bscan[b - 1] : 0;
    int rs = base + incl[i] - deg[i];
    row_start[i] = rs;
    cursor[i] = rs;
    if (i == 0) row_start[NN] = NE;
}

__global__ __launch_bounds__(256)
void scatter_kernel(const int* __restrict__ ei, int* __restrict__ cursor,
                    int* __restrict__ srcs, int* __restrict__ eid)
{
    int e = blockIdx.x * 256 + threadIdx.x;
    if (e >= NE) return;
    int s = ei[e], d = ei[NE + e];
    int pos = atomicAdd(&cursor[d], 1);
    srcs[pos] = s;
    eid[pos] = e;
}

// ---- full layer: agg (gather+f16 msgs) -> GEMM1+BN+relu -> GEMM2+relu+resid
// hb_prev (bf16 packed) read-only; hb_next write-only. 64 rows/block, 4 waves.
#define EMSGH(HV, EP)                                                       \
    {                                                                       \
        float ax = bx, ay = by;                                             \
        _Pragma("unroll")                                                   \
        for (int f = 0; f < 7; ++f) {                                       \
            half2_t av = u2h2((EP)[f]);                                     \
            ax = dot2f(av, w0h[f], ax);                                     \
            ay = dot2f(av, w1h[f], ay);                                     \
        }                                                                   \
        float hx = __uint_as_float((HV) << 16);                             \
        float hy = __uint_as_float((HV) & 0xffff0000u);                     \
        accx += fmaxf(hx + ax, 0.f);                                        \
        accy += fmaxf(hy + ay, 0.f);                                        \
    }

__global__ __launch_bounds__(256)
void layer_kernel(const uint* __restrict__ hb_prev,
                  const int* __restrict__ srcs, const int* __restrict__ row_start,
                  const uint* __restrict__ ea_h, const float* __restrict__ eW,
                  const float* __restrict__ eb,
                  const ushort* __restrict__ w1b, const float* __restrict__ b1,
                  const float* __restrict__ gamma, const float* __restrict__ beta,
                  const float* __restrict__ mean, const float* __restrict__ var,
                  const ushort* __restrict__ w2b, const float* __restrict__ b2,
                  ushort* __restrict__ hb_next, int n)
{
    __shared__ uint Ahi[64 * 64];  // bf16[64][128], XOR-swizzled; reused for z
    __shared__ uint Alo[64 * 64];
    const int t = threadIdx.x;
    const int nb = blockIdx.x * 64;
    const int w = t >> 6, lane = t & 63;
    const int c2 = lane * 2;

    // ---- edge-MLP weights: 28 consecutive floats/lane -> 14 half2 regs ----
    {
        const float4* wp = (const float4*)(eW + lane * 28);
        float4 q0 = wp[0], q1 = wp[1], q2 = wp[2], q3 = wp[3], q4 = wp[4], q5 = wp[5], q6 = wp[6];
        half2_t w0h[7], w1h[7];
        w0h[0][0]=(_Float16)q0.x; w0h[0][1]=(_Float16)q0.y;
        w0h[1][0]=(_Float16)q0.z; w0h[1][1]=(_Float16)q0.w;
        w0h[2][0]=(_Float16)q1.x; w0h[2][1]=(_Float16)q1.y;
        w0h[3][0]=(_Float16)q1.z; w0h[3][1]=(_Float16)q1.w;
        w0h[4][0]=(_Float16)q2.x; w0h[4][1]=(_Float16)q2.y;
        w0h[5][0]=(_Float16)q2.z; w0h[5][1]=(_Float16)q2.w;
        w0h[6][0]=(_Float16)q3.x; w0h[6][1]=(_Float16)q3.y;
        w1h[0][0]=(_Float16)q3.z; w1h[0][1]=(_Float16)q3.w;
        w1h[1][0]=(_Float16)q4.x; w1h[1][1]=(_Float16)q4.y;
        w1h[2][0]=(_Float16)q4.z; w1h[2][1]=(_Float16)q4.w;
        w1h[3][0]=(_Float16)q5.x; w1h[3][1]=(_Float16)q5.y;
        w1h[4][0]=(_Float16)q5.z; w1h[4][1]=(_Float16)q5.w;
        w1h[5][0]=(_Float16)q6.x; w1h[5][1]=(_Float16)q6.y;
        w1h[6][0]=(_Float16)q6.z; w1h[6][1]=(_Float16)q6.w;
        float bx = eb[c2], by = eb[c2 + 1];

        // ---- agg phase: this wave aggregates 16 nodes, writes bf16 hi/lo LDS
        for (int ni = 0; ni < 16; ++ni) {
            int rowl = w * 16 + ni;
            int node = nb + rowl;
            float accx = 0.f, accy = 0.f;
            if (node < n) {
                int beg = __builtin_amdgcn_readfirstlane(row_start[node]);
                int end = __builtin_amdgcn_readfirstlane(row_start[node + 1]);
                int j = beg;
                for (; j + 8 <= end; j += 8) {
                    int s[8];
                    uint hv[8];
#pragma unroll
                    for (int q = 0; q < 8; ++q) s[q] = srcs[j + q];
#pragma unroll
                    for (int q = 0; q < 8; ++q) hv[q] = hb_prev[(size_t)s[q] * 64 + lane];
                    const uint* e0 = ea_h + (size_t)j * 7;
                    EMSGH(hv[0], e0);      EMSGH(hv[1], e0 + 7);
                    EMSGH(hv[2], e0 + 14); EMSGH(hv[3], e0 + 21);
                    EMSGH(hv[4], e0 + 28); EMSGH(hv[5], e0 + 35);
                    EMSGH(hv[6], e0 + 42); EMSGH(hv[7], e0 + 49);
                }
                for (; j + 4 <= end; j += 4) {
                    int s0 = srcs[j], s1 = srcs[j + 1], s2 = srcs[j + 2], s3 = srcs[j + 3];
                    uint hv0 = hb_prev[(size_t)s0 * 64 + lane];
                    uint hv1 = hb_prev[(size_t)s1 * 64 + lane];
                    uint hv2 = hb_prev[(size_t)s2 * 64 + lane];
                    uint hv3 = hb_prev[(size_t)s3 * 64 + lane];
                    const uint* e0 = ea_h + (size_t)j * 7;
                    EMSGH(hv0, e0);      EMSGH(hv1, e0 + 7);
                    EMSGH(hv2, e0 + 14); EMSGH(hv3, e0 + 21);
                }
                for (; j < end; ++j) {
                    uint hv0 = hb_prev[(size_t)srcs[j] * 64 + lane];
                    const uint* e0 = ea_h + (size_t)j * 7;
                    EMSGH(hv0, e0);
                }
                uint hself = hb_prev[(size_t)node * 64 + lane];
                accx += __uint_as_float(hself << 16);
                accy += __uint_as_float(hself & 0xffff0000u);
            }
            uint h0 = bfround(accx), h1 = bfround(accy);
            float r0 = accx - __uint_as_float(h0 << 16);
            float r1 = accy - __uint_as_float(h1 << 16);
            uint byte = ((uint)(rowl * 256 + c2 * 2)) ^ ((rowl & 7) << 4);
            *(uint*)((char*)Ahi + byte) = h0 | (h1 << 16);
            *(uint*)((char*)Alo + byte) = bfround(r0) | (bfround(r1) << 16);
        }
    }

    // ---- GEMM weight fragments ----
    const int lc = lane & 15, lk = lane >> 4;
    bf16x8 wf1[2][4], wf2[2][4];
#pragma unroll
    for (int ct = 0; ct < 2; ++ct)
#pragma unroll
        for (int ks = 0; ks < 4; ++ks) {
            size_t off = (size_t)(w * 32 + ct * 16 + lc) * HD + ks * 32 + lk * 8;
            wf1[ct][ks] = *(const bf16x8*)(w1b + off);
            wf2[ct][ks] = *(const bf16x8*)(w2b + off);
        }

    __syncthreads();

    // ---- GEMM1: hi/lo bf16 ----
    f32x4 acc[4][2];
#pragma unroll
    for (int rt = 0; rt < 4; ++rt)
#pragma unroll
        for (int ct = 0; ct < 2; ++ct) acc[rt][ct] = (f32x4){0.f, 0.f, 0.f, 0.f};

#pragma unroll
    for (int ks = 0; ks < 4; ++ks) {
#pragma unroll
        for (int rt = 0; rt < 4; ++rt) {
            int row = rt * 16 + lc;
            uint byte = ((uint)(row * 256 + (ks * 32 + lk * 8) * 2)) ^ ((row & 7) << 4);
            bf16x8 ah = *(const bf16x8*)((char*)Ahi + byte);
            bf16x8 al = *(const bf16x8*)((char*)Alo + byte);
            acc[rt][0] = __builtin_amdgcn_mfma_f32_16x16x32_bf16(ah, wf1[0][ks], acc[rt][0], 0, 0, 0);
            acc[rt][0] = __builtin_amdgcn_mfma_f32_16x16x32_bf16(al, wf1[0][ks], acc[rt][0], 0, 0, 0);
            acc[rt][1] = __builtin_amdgcn_mfma_f32_16x16x32_bf16(ah, wf1[1][ks], acc[rt][1], 0, 0, 0);
            acc[rt][1] = __builtin_amdgcn_mfma_f32_16x16x32_bf16(al, wf1[1][ks], acc[rt][1], 0, 0, 0);
        }
    }

    __syncthreads();

    // ---- epilogue1: BN + relu -> z bf16 into Ahi ----
#pragma unroll
    for (int ct = 0; ct < 2; ++ct) {
        int col = w * 32 + ct * 16 + lc;
        float bi = b1[col];
        float scv = gamma[col] * rsqrtf(var[col] + BN_EPS);
        float shv = beta[col] - mean[col] * scv;
#pragma unroll
        for (int rt = 0; rt < 4; ++rt) {
#pragma unroll
            for (int r = 0; r < 4; ++r) {
                int rowl = rt * 16 + lk * 4 + r;
                float v = (acc[rt][ct][r] + bi) * scv + shv;
                v = fmaxf(v, 0.f);
                uint byte = ((uint)(rowl * 256 + col * 2)) ^ ((rowl & 7) << 4);
                *(ushort*)((char*)Ahi + byte) = (ushort)bfround(v);
            }
        }
    }

    __syncthreads();

    // ---- GEMM2: single bf16 ----
    f32x4 acc2[4][2];
#pragma unroll
    for (int rt = 0; rt < 4; ++rt)
#pragma unroll
        for (int ct = 0; ct < 2; ++ct) acc2[rt][ct] = (f32x4){0.f, 0.f, 0.f, 0.f};

#pragma unroll
    for (int ks = 0; ks < 4; ++ks) {
#pragma unroll
        for (int rt = 0; rt < 4; ++rt) {
            int row = rt * 16 + lc;
            uint byte = ((uint)(row * 256 + (ks * 32 + lk * 8) * 2)) ^ ((row & 7) << 4);
            bf16x8 az = *(const bf16x8*)((char*)Ahi + byte);
            acc2[rt][0] = __builtin_amdgcn_mfma_f32_16x16x32_bf16(az, wf2[0][ks], acc2[rt][0], 0, 0, 0);
            acc2[rt][1] = __builtin_amdgcn_mfma_f32_16x16x32_bf16(az, wf2[1][ks], acc2[rt][1], 0, 0, 0);
        }
    }

    // ---- epilogue2: relu + bf16 residual; write hb_next ----
    const ushort* hp16 = (const ushort*)hb_prev;
#pragma unroll
    for (int ct = 0; ct < 2; ++ct) {
        int col = w * 32 + ct * 16 + lc;
        float bi = b2[col];
#pragma unroll
        for (int rt = 0; rt < 4; ++rt) {
#pragma unroll
            for (int r = 0; r < 4; ++r) {
                int row = nb + rt * 16 + lk * 4 + r;
                if (row < n) {
                    float hprev = __uint_as_float(((uint)hp16[(size_t)row * HD + col]) << 16);
                    float v = fmaxf(acc2[rt][ct][r] + bi, 0.f) + hprev;
                    hb_next[(size_t)row * HD + col] = (ushort)bfround(v);
                }
            }
        }
    }
}

// -------- pooling over bf16 h: chunked local sums, rare atomics ----
__global__ __launch_bounds__(128)
void pool_kernel(const ushort* __restrict__ hb, const int* __restrict__ batch,
                 float* __restrict__ pooled, int* __restrict__ counts, int n, int chunk)
{
    int c = threadIdx.x;
    int n_start = blockIdx.x * chunk;
    if (n_start >= n) return;
    int n_end = min(n_start + chunk, n);
    float local = 0.f;
    int cnt = 0;
    int g_cur = batch[n_start];
    for (int nd = n_start; nd < n_end; ++nd) {
        int g = batch[nd];
        if (g != g_cur) {
            atomicAdd(&pooled[g_cur * HD + c], local);
            if (c == 0) atomicAdd(&counts[g_cur], cnt);
            local = 0.f; cnt = 0; g_cur = g;
        }
        local += __uint_as_float(((uint)hb[(size_t)nd * HD + c]) << 16);
        cnt++;
    }
    atomicAdd(&pooled[g_cur * HD + c], local);
    if (c == 0) atomicAdd(&counts[g_cur], cnt);
}

__global__ __launch_bounds__(128)
void final_kernel(const float* __restrict__ pooled, const int* __restrict__ counts,
                  const float* __restrict__ projT, const float* __restrict__ pb,
                  float* __restrict__ out)
{
    __shared__ float p_lds[HD];
    int g = blockIdx.x, p = threadIdx.x;
    float inv = 1.f / fmaxf((float)counts[g], 1.f);
    p_lds[p] = pooled[g * HD + p];
    __syncthreads();
    float acc = 0.f;
#pragma unroll 4
    for (int c = 0; c < HD; ++c) acc += p_lds[c] * projT[c * HD + p];
    out[g * HD + p] = acc * inv + pb[p];
}

extern "C" void kernel_launch(void* const* d_in, const int* in_sizes, int n_in,
                              void* d_out, int out_size, void* d_ws, size_t ws_size,
                              hipStream_t stream)
{
    const float* x        = (const float*)d_in[0];
    const int*   edge_idx = (const int*)d_in[1];
    const float* edge_attr= (const float*)d_in[2];
    const int*   batch    = (const int*)d_in[3];
    const float* node_W   = (const float*)d_in[4];
    const float* node_b   = (const float*)d_in[5];
    const float* edge_W   = (const float*)d_in[6];
    const float* edge_b   = (const float*)d_in[7];
    const float* lin1_b   = (const float*)d_in[9];
    const float* bn_gamma = (const float*)d_in[10];
    const float* bn_beta  = (const float*)d_in[11];
    const float* bn_mean  = (const float*)d_in[12];
    const float* bn_var   = (const float*)d_in[13];
    const float* lin2_b   = (const float*)d_in[15];
    const float* proj_b   = (const float*)d_in[17];

    char* ws = (char*)d_ws;
    uint*   hbA      = (uint*)  (ws);                  // 12.8 MB
    uint*   hbB      = (uint*)  (ws + 12800000);       // 12.8 MB
    uint*   ea_h     = (uint*)  (ws + 25600000);       // 22.4 MB
    int*    srcs     = (int*)   (ws + 48000000);       // 3.2 MB
    int*    eid      = (int*)   (ws + 51200000);       // 3.2 MB
    ushort* wb       = (ushort*)(ws + 54400000);       // 196,608
    float*  projT    = (float*) (ws + 54600000);       // 65,536
    float*  pooled   = (float*) (ws + 54700000);       // 32,768
    int*    counts   = (int*)   (ws + 54732768);       // 256
    int*    deg      = (int*)   (ws + 54740000);       // 200,000
    int*    incl     = (int*)   (ws + 54940000);       // 200,000
    int*    bsum     = (int*)   (ws + 55140000);       // 1,024
    int*    bscan    = (int*)   (ws + 55142048);       // 1,024
    int*    row_start= (int*)   (ws + 55144096);       // 200,064
    int*    cursor   = (int*)   (ws + 55344160);       // 200,000

    const int NB = (NN + 255) / 256;  // 196

    // --- CSR build (edge_index constant across layers) ---
    hipMemsetAsync(deg, 0, NN * sizeof(int), stream);
    hist_kernel<<<(NE + 255) / 256, 256, 0, stream>>>(edge_idx, deg);
    scan1_kernel<<<NB, 256, 0, stream>>>(deg, incl, bsum);
    scan2_kernel<<<1, 256, 0, stream>>>(bsum, bscan, NB);
    scan3_kernel<<<NB, 256, 0, stream>>>(deg, incl, bscan, row_start, cursor);
    scatter_kernel<<<(NE + 255) / 256, 256, 0, stream>>>(edge_idx, cursor, srcs, eid);

    // --- init: weights + node embed (hbA) + ea f16 permute ---
    init_kernel<<<448 + 12500 + 25000, 256, 0, stream>>>(
        x, node_W, node_b, (const float*)d_in[8], (const float*)d_in[14],
        (const float*)d_in[16], edge_attr, eid, hbA, ea_h, wb, projT);

    // --- 3 fused layers, hb double-buffered ---
    uint* prev = hbA; uint* next = hbB;
    for (int i = 0; i < NL; ++i) {
        layer_kernel<<<(NN + 63) / 64, 256, 0, stream>>>(
            prev, srcs, row_start, ea_h, edge_W, edge_b,
            wb + (size_t)i * HD * HD, lin1_b + i * HD,
            bn_gamma + i * HD, bn_beta + i * HD, bn_mean + i * HD, bn_var + i * HD,
            wb + (size_t)(3 + i) * HD * HD, lin2_b + i * HD,
            (ushort*)next, NN);
        uint* tmp = prev; prev = next; next = tmp;
    }

    hipMemsetAsync(pooled, 0, NG * HD * sizeof(float) + NG * sizeof(int) + 4000, stream);
    pool_kernel<<<(NN + 31) / 32, 128, 0, stream>>>((const ushort*)prev, batch, pooled, counts, NN, 32);
    final_kernel<<<NG, HD, 0, stream>>>(pooled, counts, projT, proj_b, (float*)d_out);
}

// Round 13
// 431.730 us; speedup vs baseline: 1.4361x; 1.4361x over previous
//
#include <hip/hip_runtime.h>

typedef unsigned int uint;
typedef unsigned short ushort;
typedef __attribute__((ext_vector_type(8))) short bf16x8;
typedef __attribute__((ext_vector_type(4))) float f32x4;
typedef __attribute__((ext_vector_type(2))) _Float16 half2_t;

#define NN 50000
#define NE 800000
#define NG 64
#define NODE_F 11
#define EDGE_F 14
#define HD 128
#define NL 3
#define BN_EPS 1e-5f

#if defined(__has_builtin)
#if __has_builtin(__builtin_amdgcn_fdot2)
#define HAS_DOT2 1
#endif
#endif

__device__ __forceinline__ uint bfround(float v) {
    uint b = __float_as_uint(v);
    return (b + 0x7fffu + ((b >> 16) & 1u)) >> 16;
}

__device__ __forceinline__ float dot2f(half2_t a, half2_t b, float acc) {
#ifdef HAS_DOT2
    return __builtin_amdgcn_fdot2(a, b, acc, false);
#else
    return acc + (float)a[0] * (float)b[0] + (float)a[1] * (float)b[1];
#endif
}

__device__ __forceinline__ half2_t u2h2(uint u) {
    return __builtin_bit_cast(half2_t, u);
}

// --- init: weights prep (blocks<448) + node embed->hb (middle) + ea f16 permute (rest)
__global__ __launch_bounds__(256)
void init_kernel(const float* __restrict__ x, const float* __restrict__ nW,
                 const float* __restrict__ nb_, const float* __restrict__ lin1,
                 const float* __restrict__ lin2, const float* __restrict__ proj,
                 const float* __restrict__ ea, const int* __restrict__ eid,
                 uint* __restrict__ hb, uint* __restrict__ ea_h,
                 ushort* __restrict__ wb, float* __restrict__ projT)
{
    int bid = blockIdx.x;
    if (bid < 448) {
        int idx = bid * 256 + threadIdx.x;
        if (idx < 6 * HD * HD) {
            int m = idx >> 14, e = idx & (HD * HD - 1);
            const float* src = (m < 3) ? (lin1 + m * HD * HD) : (lin2 + (m - 3) * HD * HD);
            wb[idx] = (ushort)bfround(src[e]);
        } else if (idx < 7 * HD * HD) {
            int e = idx - 6 * HD * HD;
            int r = e >> 7, c = e & 127;
            projT[c * HD + r] = proj[r * HD + c];
        }
    } else if (bid < 448 + 12500) {
        int idx = (bid - 448) * 256 + threadIdx.x;
        int node = idx >> 6, cp = idx & 63;
        int c2 = cp * 2;
        const float* xr = x + node * NODE_F;
        const float* w0 = nW + c2 * NODE_F;
        const float* w1 = w0 + NODE_F;
        float a0 = nb_[c2], a1 = nb_[c2 + 1];
#pragma unroll
        for (int f = 0; f < NODE_F; ++f) { float xv = xr[f]; a0 += xv * w0[f]; a1 += xv * w1[f]; }
        hb[idx] = bfround(a0) | (bfround(a1) << 16);
    } else {
        int idx = (bid - 448 - 12500) * 256 + threadIdx.x;
        int el = idx >> 3, f2 = idx & 7;
        if (f2 >= 7) return;
        float2 v = *(const float2*)(ea + (size_t)eid[el] * EDGE_F + 2 * f2);
        half2_t hh;
        hh[0] = (_Float16)v.x;
        hh[1] = (_Float16)v.y;
        ea_h[(size_t)el * 7 + f2] = __builtin_bit_cast(uint, hh);
    }
}

// ----------------------------- CSR construction ----------------------------
__global__ __launch_bounds__(256)
void hist_kernel(const int* __restrict__ ei, int* __restrict__ deg)
{
    int e = blockIdx.x * 256 + threadIdx.x;
    if (e < NE) atomicAdd(&deg[ei[NE + e]], 1);
}

__global__ __launch_bounds__(256)
void scan1_kernel(const int* __restrict__ deg, int* __restrict__ incl, int* __restrict__ bsum)
{
    int i = blockIdx.x * 256 + threadIdx.x;
    int v = (i < NN) ? deg[i] : 0;
    int lane = threadIdx.x & 63;
#pragma unroll
    for (int off = 1; off < 64; off <<= 1) {
        int u = __shfl_up(v, off);
        if (lane >= off) v += u;
    }
    __shared__ int wsum[4];
    if (lane == 63) wsum[threadIdx.x >> 6] = v;
    __syncthreads();
    int wid = threadIdx.x >> 6;
    int add = 0;
#pragma unroll
    for (int w = 0; w < 3; ++w) if (w < wid) add += wsum[w];
    v += add;
    if (i < NN) incl[i] = v;
    if (threadIdx.x == 255) bsum[blockIdx.x] = v;
}

__global__ __launch_bounds__(256)
void scan2_kernel(const int* __restrict__ bsum, int* __restrict__ bscan, int nb)
{
    int i = threadIdx.x;
    int v = (i < nb) ? bsum[i] : 0;
    int lane = i & 63;
#pragma unroll
    for (int off = 1; off < 64; off <<= 1) {
        int u = __shfl_up(v, off);
        if (lane >= off) v += u;
    }
    __shared__ int wsum[4];
    if (lane == 63) wsum[i >> 6] = v;
    __syncthreads();
    int wid = i >> 6;
    int add = 0;
#pragma unroll
    for (int w = 0; w < 3; ++w) if (w < wid) add += wsum[w];
    v += add;
    bscan[i] = v;
}

__global__ __launch_bounds__(256)
void scan3_kernel(const int* __restrict__ deg, const int* __restrict__ incl,
                  const int* __restrict__ bscan, int* __restrict__ row_start,
                  int* __restrict__ cursor)
{
    int i = blockIdx.x * 256 + threadIdx.x;
    if (i >= NN) return;
    int b = blockIdx.x;
    int base = (b > 0) ? bscan[b - 1] : 0;
    int rs = base + incl[i] - deg[i];
    row_start[i] = rs;
    cursor[i] = rs;
    if (i == 0) row_start[NN] = NE;
}

__global__ __launch_bounds__(256)
void scatter_kernel(const int* __restrict__ ei, int* __restrict__ cursor,
                    int* __restrict__ srcs, int* __restrict__ eid)
{
    int e = blockIdx.x * 256 + threadIdx.x;
    if (e >= NE) return;
    int s = ei[e], d = ei[NE + e];
    int pos = atomicAdd(&cursor[d], 1);
    srcs[pos] = s;
    eid[pos] = e;
}

// --- agg: zin[n] = hb[n] + sum_j relu(hb[src_j] + f16dot(ea_h[j], eW) + eb) --
// 1 wave/node, 2 ch/lane; weights as 14 half2 regs/lane; v_dot2_f32_f16.
#define EMSGH(HV, EP)                                                       \
    {                                                                       \
        float ax = bx, ay = by;                                             \
        _Pragma("unroll")                                                   \
        for (int f = 0; f < 7; ++f) {                                       \
            half2_t av = u2h2((EP)[f]);                                     \
            ax = dot2f(av, w0h[f], ax);                                     \
            ay = dot2f(av, w1h[f], ay);                                     \
        }                                                                   \
        float hx = __uint_as_float((HV) << 16);                             \
        float hy = __uint_as_float((HV) & 0xffff0000u);                     \
        accx += fmaxf(hx + ax, 0.f);                                        \
        accy += fmaxf(hy + ay, 0.f);                                        \
    }

__global__ __launch_bounds__(256)
void agg_f16_kernel(const uint* __restrict__ hb,
                    const int* __restrict__ srcs, const int* __restrict__ row_start,
                    const uint* __restrict__ ea_h, const float* __restrict__ eW,
                    const float* __restrict__ eb, float* __restrict__ zin)
{
    int node = blockIdx.x * 4 + (threadIdx.x >> 6);
    if (node >= NN) return;
    int lane = threadIdx.x & 63;
    int c2 = lane * 2;
    const float4* wp = (const float4*)(eW + lane * 28);
    float4 q0 = wp[0], q1 = wp[1], q2 = wp[2], q3 = wp[3], q4 = wp[4], q5 = wp[5], q6 = wp[6];
    half2_t w0h[7], w1h[7];
    w0h[0][0]=(_Float16)q0.x; w0h[0][1]=(_Float16)q0.y;
    w0h[1][0]=(_Float16)q0.z; w0h[1][1]=(_Float16)q0.w;
    w0h[2][0]=(_Float16)q1.x; w0h[2][1]=(_Float16)q1.y;
    w0h[3][0]=(_Float16)q1.z; w0h[3][1]=(_Float16)q1.w;
    w0h[4][0]=(_Float16)q2.x; w0h[4][1]=(_Float16)q2.y;
    w0h[5][0]=(_Float16)q2.z; w0h[5][1]=(_Float16)q2.w;
    w0h[6][0]=(_Float16)q3.x; w0h[6][1]=(_Float16)q3.y;
    w1h[0][0]=(_Float16)q3.z; w1h[0][1]=(_Float16)q3.w;
    w1h[1][0]=(_Float16)q4.x; w1h[1][1]=(_Float16)q4.y;
    w1h[2][0]=(_Float16)q4.z; w1h[2][1]=(_Float16)q4.w;
    w1h[3][0]=(_Float16)q5.x; w1h[3][1]=(_Float16)q5.y;
    w1h[4][0]=(_Float16)q5.z; w1h[4][1]=(_Float16)q5.w;
    w1h[5][0]=(_Float16)q6.x; w1h[5][1]=(_Float16)q6.y;
    w1h[6][0]=(_Float16)q6.z; w1h[6][1]=(_Float16)q6.w;
    float bx = eb[c2], by = eb[c2 + 1];
    float accx = 0.f, accy = 0.f;
    int beg = __builtin_amdgcn_readfirstlane(row_start[node]);
    int end = __builtin_amdgcn_readfirstlane(row_start[node + 1]);
    int j = beg;
    for (; j + 8 <= end; j += 8) {
        int s[8];
        uint hv[8];
#pragma unroll
        for (int q = 0; q < 8; ++q) s[q] = srcs[j + q];
#pragma unroll
        for (int q = 0; q < 8; ++q) hv[q] = hb[(size_t)s[q] * 64 + lane];
        const uint* e0 = ea_h + (size_t)j * 7;
        EMSGH(hv[0], e0);      EMSGH(hv[1], e0 + 7);
        EMSGH(hv[2], e0 + 14); EMSGH(hv[3], e0 + 21);
        EMSGH(hv[4], e0 + 28); EMSGH(hv[5], e0 + 35);
        EMSGH(hv[6], e0 + 42); EMSGH(hv[7], e0 + 49);
    }
    for (; j + 4 <= end; j += 4) {
        int s0 = srcs[j], s1 = srcs[j + 1], s2 = srcs[j + 2], s3 = srcs[j + 3];
        uint hv0 = hb[(size_t)s0 * 64 + lane];
        uint hv1 = hb[(size_t)s1 * 64 + lane];
        uint hv2 = hb[(size_t)s2 * 64 + lane];
        uint hv3 = hb[(size_t)s3 * 64 + lane];
        const uint* e0 = ea_h + (size_t)j * 7;
        EMSGH(hv0, e0);      EMSGH(hv1, e0 + 7);
        EMSGH(hv2, e0 + 14); EMSGH(hv3, e0 + 21);
    }
    for (; j < end; ++j) {
        uint hv0 = hb[(size_t)srcs[j] * 64 + lane];
        const uint* e0 = ea_h + (size_t)j * 7;
        EMSGH(hv0, e0);
    }
    uint hself = hb[(size_t)node * 64 + lane];
    accx += __uint_as_float(hself << 16);
    accy += __uint_as_float(hself & 0xffff0000u);
    *(float2*)&zin[(size_t)node * HD + c2] = make_float2(accx, accy);
}

// --------- fused layer: hb = bf16(relu(relu(BN(zin@W1^T+b1))@W2^T+b2) + hb) --
// In-place hb safe: each block reads/writes only its own 64 rows.
__global__ __launch_bounds__(256)
void fused_layer_kernel(const float* __restrict__ zin,
                        const ushort* __restrict__ w1b, const float* __restrict__ b1,
                        const float* __restrict__ gamma, const float* __restrict__ beta,
                        const float* __restrict__ mean, const float* __restrict__ var,
                        const ushort* __restrict__ w2b, const float* __restrict__ b2,
                        ushort* __restrict__ hb, int n)
{
    __shared__ uint Ahi[64 * 64];  // bf16[64][128], XOR-swizzled; reused for z
    __shared__ uint Alo[64 * 64];
    const int t = threadIdx.x;
    const int nb = blockIdx.x * 64;

    {
        int row = t >> 2;
        int kq = (t & 3) * 32;
        int gn = nb + row;
        uint hiw[16], low[16];
        if (gn < n) {
            const float4* src = (const float4*)(zin + (size_t)gn * HD + kq);
#pragma unroll
            for (int i = 0; i < 8; ++i) {
                float4 v = src[i];
                uint h0 = bfround(v.x), h1 = bfround(v.y), h2 = bfround(v.z), h3 = bfround(v.w);
                float r0 = v.x - __uint_as_float(h0 << 16);
                float r1 = v.y - __uint_as_float(h1 << 16);
                float r2 = v.z - __uint_as_float(h2 << 16);
                float r3 = v.w - __uint_as_float(h3 << 16);
                hiw[2 * i]     = h0 | (h1 << 16);
                hiw[2 * i + 1] = h2 | (h3 << 16);
                low[2 * i]     = bfround(r0) | (bfround(r1) << 16);
                low[2 * i + 1] = bfround(r2) | (bfround(r3) << 16);
            }
        } else {
#pragma unroll
            for (int i = 0; i < 16; ++i) { hiw[i] = 0; low[i] = 0; }
        }
        uint rowbase = row * 256;
#pragma unroll
        for (int i = 0; i < 4; ++i) {
            uint byte = (rowbase + (kq + 8 * i) * 2) ^ ((row & 7) << 4);
            *(uint4*)((char*)Ahi + byte) = make_uint4(hiw[4 * i], hiw[4 * i + 1], hiw[4 * i + 2], hiw[4 * i + 3]);
            *(uint4*)((char*)Alo + byte) = make_uint4(low[4 * i], low[4 * i + 1], low[4 * i + 2], low[4 * i + 3]);
        }
    }

    const int w  = t >> 6, l = t & 63;
    const int lc = l & 15, lk = l >> 4;
    bf16x8 wf1[2][4], wf2[2][4];
#pragma unroll
    for (int ct = 0; ct < 2; ++ct)
#pragma unroll
        for (int ks = 0; ks < 4; ++ks) {
            size_t off = (size_t)(w * 32 + ct * 16 + lc) * HD + ks * 32 + lk * 8;
            wf1[ct][ks] = *(const bf16x8*)(w1b + off);
            wf2[ct][ks] = *(const bf16x8*)(w2b + off);
        }

    __syncthreads();

    f32x4 acc[4][2];
#pragma unroll
    for (int rt = 0; rt < 4; ++rt)
#pragma unroll
        for (int ct = 0; ct < 2; ++ct) acc[rt][ct] = (f32x4){0.f, 0.f, 0.f, 0.f};

#pragma unroll
    for (int ks = 0; ks < 4; ++ks) {
#pragma unroll
        for (int rt = 0; rt < 4; ++rt) {
            int row = rt * 16 + lc;
            uint byte = ((uint)(row * 256 + (ks * 32 + lk * 8) * 2)) ^ ((row & 7) << 4);
            bf16x8 ah = *(const bf16x8*)((char*)Ahi + byte);
            bf16x8 al = *(const bf16x8*)((char*)Alo + byte);
            acc[rt][0] = __builtin_amdgcn_mfma_f32_16x16x32_bf16(ah, wf1[0][ks], acc[rt][0], 0, 0, 0);
            acc[rt][0] = __builtin_amdgcn_mfma_f32_16x16x32_bf16(al, wf1[0][ks], acc[rt][0], 0, 0, 0);
            acc[rt][1] = __builtin_amdgcn_mfma_f32_16x16x32_bf16(ah, wf1[1][ks], acc[rt][1], 0, 0, 0);
            acc[rt][1] = __builtin_amdgcn_mfma_f32_16x16x32_bf16(al, wf1[1][ks], acc[rt][1], 0, 0, 0);
        }
    }

    __syncthreads();

#pragma unroll
    for (int ct = 0; ct < 2; ++ct) {
        int col = w * 32 + ct * 16 + lc;
        float bi = b1[col];
        float scv = gamma[col] * rsqrtf(var[col] + BN_EPS);
        float shv = beta[col] - mean[col] * scv;
#pragma unroll
        for (int rt = 0; rt < 4; ++rt) {
#pragma unroll
            for (int r = 0; r < 4; ++r) {
                int rowl = rt * 16 + lk * 4 + r;
                float v = (acc[rt][ct][r] + bi) * scv + shv;
                v = fmaxf(v, 0.f);
                uint byte = ((uint)(rowl * 256 + col * 2)) ^ ((rowl & 7) << 4);
                *(ushort*)((char*)Ahi + byte) = (ushort)bfround(v);
            }
        }
    }

    __syncthreads();

    f32x4 acc2[4][2];
#pragma unroll
    for (int rt = 0; rt < 4; ++rt)
#pragma unroll
        for (int ct = 0; ct < 2; ++ct) acc2[rt][ct] = (f32x4){0.f, 0.f, 0.f, 0.f};

#pragma unroll
    for (int ks = 0; ks < 4; ++ks) {
#pragma unroll
        for (int rt = 0; rt < 4; ++rt) {
            int row = rt * 16 + lc;
            uint byte = ((uint)(row * 256 + (ks * 32 + lk * 8) * 2)) ^ ((row & 7) << 4);
            bf16x8 az = *(const bf16x8*)((char*)Ahi + byte);
            acc2[rt][0] = __builtin_amdgcn_mfma_f32_16x16x32_bf16(az, wf2[0][ks], acc2[rt][0], 0, 0, 0);
            acc2[rt][1] = __builtin_amdgcn_mfma_f32_16x16x32_bf16(az, wf2[1][ks], acc2[rt][1], 0, 0, 0);
        }
    }

#pragma unroll
    for (int ct = 0; ct < 2; ++ct) {
        int col = w * 32 + ct * 16 + lc;
        float bi = b2[col];
#pragma unroll
        for (int rt = 0; rt < 4; ++rt) {
#pragma unroll
            for (int r = 0; r < 4; ++r) {
                int row = nb + rt * 16 + lk * 4 + r;
                if (row < n) {
                    float hprev = __uint_as_float(((uint)hb[(size_t)row * HD + col]) << 16);
                    float v = fmaxf(acc2[rt][ct][r] + bi, 0.f) + hprev;
                    hb[(size_t)row * HD + col] = (ushort)bfround(v);
                }
            }
        }
    }
}

// -------- pooling over bf16 h: chunked local sums, rare atomics ----
__global__ __launch_bounds__(128)
void pool_kernel(const ushort* __restrict__ hb, const int* __restrict__ batch,
                 float* __restrict__ pooled, int* __restrict__ counts, int n, int chunk)
{
    int c = threadIdx.x;
    int n_start = blockIdx.x * chunk;
    if (n_start >= n) return;
    int n_end = min(n_start + chunk, n);
    float local = 0.f;
    int cnt = 0;
    int g_cur = batch[n_start];
    for (int nd = n_start; nd < n_end; ++nd) {
        int g = batch[nd];
        if (g != g_cur) {
            atomicAdd(&pooled[g_cur * HD + c], local);
            if (c == 0) atomicAdd(&counts[g_cur], cnt);
            local = 0.f; cnt = 0; g_cur = g;
        }
        local += __uint_as_float(((uint)hb[(size_t)nd * HD + c]) << 16);
        cnt++;
    }
    atomicAdd(&pooled[g_cur * HD + c], local);
    if (c == 0) atomicAdd(&counts[g_cur], cnt);
}

__global__ __launch_bounds__(128)
void final_kernel(const float* __restrict__ pooled, const int* __restrict__ counts,
                  const float* __restrict__ projT, const float* __restrict__ pb,
                  float* __restrict__ out)
{
    __shared__ float p_lds[HD];
    int g = blockIdx.x, p = threadIdx.x;
    float inv = 1.f / fmaxf((float)counts[g], 1.f);
    p_lds[p] = pooled[g * HD + p];
    __syncthreads();
    float acc = 0.f;
#pragma unroll 4
    for (int c = 0; c < HD; ++c) acc += p_lds[c] * projT[c * HD + p];
    out[g * HD + p] = acc * inv + pb[p];
}

extern "C" void kernel_launch(void* const* d_in, const int* in_sizes, int n_in,
                              void* d_out, int out_size, void* d_ws, size_t ws_size,
                              hipStream_t stream)
{
    const float* x        = (const float*)d_in[0];
    const int*   edge_idx = (const int*)d_in[1];
    const float* edge_attr= (const float*)d_in[2];
    const int*   batch    = (const int*)d_in[3];
    const float* node_W   = (const float*)d_in[4];
    const float* node_b   = (const float*)d_in[5];
    const float* edge_W   = (const float*)d_in[6];
    const float* edge_b   = (const float*)d_in[7];
    const float* lin1_b   = (const float*)d_in[9];
    const float* bn_gamma = (const float*)d_in[10];
    const float* bn_beta  = (const float*)d_in[11];
    const float* bn_mean  = (const float*)d_in[12];
    const float* bn_var   = (const float*)d_in[13];
    const float* lin2_b   = (const float*)d_in[15];
    const float* proj_b   = (const float*)d_in[17];

    char* ws = (char*)d_ws;
    uint*   hb       = (uint*)  (ws);                  // 12.8 MB (bf16 packed, 2ch/uint)
    float*  zin      = (float*) (ws + 12800000);       // 25.6 MB
    uint*   ea_h     = (uint*)  (ws + 38400000);       // 22.4 MB
    int*    srcs     = (int*)   (ws + 60800000);       // 3.2 MB
    int*    eid      = (int*)   (ws + 64000000);       // 3.2 MB
    ushort* wb       = (ushort*)(ws + 67200000);       // 196,608
    float*  projT    = (float*) (ws + 67400000);       // 65,536
    float*  pooled   = (float*) (ws + 67500000);       // 32,768
    int*    counts   = (int*)   (ws + 67532768);       // 256
    int*    deg      = (int*)   (ws + 67540000);       // 200,000
    int*    incl     = (int*)   (ws + 67740000);       // 200,000
    int*    bsum     = (int*)   (ws + 67940000);       // 1,024
    int*    bscan    = (int*)   (ws + 67942048);       // 1,024
    int*    row_start= (int*)   (ws + 67944096);       // 200,064
    int*    cursor   = (int*)   (ws + 68144160);       // 200,000

    const int NB = (NN + 255) / 256;  // 196

    // --- CSR build (edge_index constant across layers) ---
    hipMemsetAsync(deg, 0, NN * sizeof(int), stream);
    hist_kernel<<<(NE + 255) / 256, 256, 0, stream>>>(edge_idx, deg);
    scan1_kernel<<<NB, 256, 0, stream>>>(deg, incl, bsum);
    scan2_kernel<<<1, 256, 0, stream>>>(bsum, bscan, NB);
    scan3_kernel<<<NB, 256, 0, stream>>>(deg, incl, bscan, row_start, cursor);
    scatter_kernel<<<(NE + 255) / 256, 256, 0, stream>>>(edge_idx, cursor, srcs, eid);

    // --- init: weights + node embed (hb) + ea f16 permute ---
    init_kernel<<<448 + 12500 + 25000, 256, 0, stream>>>(
        x, node_W, node_b, (const float*)d_in[8], (const float*)d_in[14],
        (const float*)d_in[16], edge_attr, eid, hb, ea_h, wb, projT);

    for (int i = 0; i < NL; ++i) {
        agg_f16_kernel<<<(NN + 3) / 4, 256, 0, stream>>>(
            hb, srcs, row_start, ea_h, edge_W, edge_b, zin);
        fused_layer_kernel<<<(NN + 63) / 64, 256, 0, stream>>>(
            zin, wb + (size_t)i * HD * HD, lin1_b + i * HD,
            bn_gamma + i * HD, bn_beta + i * HD, bn_mean + i * HD, bn_var + i * HD,
            wb + (size_t)(3 + i) * HD * HD, lin2_b + i * HD,
            (ushort*)hb, NN);
    }

    hipMemsetAsync(pooled, 0, NG * HD * sizeof(float) + NG * sizeof(int) + 4000, stream);
    pool_kernel<<<(NN + 31) / 32, 128, 0, stream>>>((const ushort*)hb, batch, pooled, counts, NN, 32);
    final_kernel<<<NG, HD, 0, stream>>>(pooled, counts, projT, proj_b, (float*)d_out);
}

// Round 14
// 412.947 us; speedup vs baseline: 1.5014x; 1.0455x over previous
//
#include <hip/hip_runtime.h>

typedef unsigned int uint;
typedef unsigned short ushort;
typedef __attribute__((ext_vector_type(8))) short bf16x8;
typedef __attribute__((ext_vector_type(4))) float f32x4;
typedef __attribute__((ext_vector_type(2))) _Float16 half2_t;

#define NN 50000
#define NE 800000
#define NG 64
#define NODE_F 11
#define EDGE_F 14
#define HD 128
#define NL 3
#define BN_EPS 1e-5f

#if defined(__has_builtin)
#if __has_builtin(__builtin_amdgcn_fdot2)
#define HAS_DOT2 1
#endif
#endif

__device__ __forceinline__ uint bfround(float v) {
    uint b = __float_as_uint(v);
    return (b + 0x7fffu + ((b >> 16) & 1u)) >> 16;
}

__device__ __forceinline__ float dot2f(half2_t a, half2_t b, float acc) {
#ifdef HAS_DOT2
    return __builtin_amdgcn_fdot2(a, b, acc, false);
#else
    return acc + (float)a[0] * (float)b[0] + (float)a[1] * (float)b[1];
#endif
}

__device__ __forceinline__ half2_t u2h2(uint u) {
    return __builtin_bit_cast(half2_t, u);
}

// --- init: weights prep (blocks<448) + node embed->hb (middle) + ea f16 permute (rest)
__global__ __launch_bounds__(256)
void init_kernel(const float* __restrict__ x, const float* __restrict__ nW,
                 const float* __restrict__ nb_, const float* __restrict__ lin1,
                 const float* __restrict__ lin2, const float* __restrict__ proj,
                 const float* __restrict__ ea, const int* __restrict__ eid,
                 uint* __restrict__ hb, uint* __restrict__ ea_h,
                 ushort* __restrict__ wb, float* __restrict__ projT)
{
    int bid = blockIdx.x;
    if (bid < 448) {
        int idx = bid * 256 + threadIdx.x;
        if (idx < 6 * HD * HD) {
            int m = idx >> 14, e = idx & (HD * HD - 1);
            const float* src = (m < 3) ? (lin1 + m * HD * HD) : (lin2 + (m - 3) * HD * HD);
            wb[idx] = (ushort)bfround(src[e]);
        } else if (idx < 7 * HD * HD) {
            int e = idx - 6 * HD * HD;
            int r = e >> 7, c = e & 127;
            projT[c * HD + r] = proj[r * HD + c];
        }
    } else if (bid < 448 + 12500) {
        int idx = (bid - 448) * 256 + threadIdx.x;
        int node = idx >> 6, cp = idx & 63;
        int c2 = cp * 2;
        const float* xr = x + node * NODE_F;
        const float* w0 = nW + c2 * NODE_F;
        const float* w1 = w0 + NODE_F;
        float a0 = nb_[c2], a1 = nb_[c2 + 1];
#pragma unroll
        for (int f = 0; f < NODE_F; ++f) { float xv = xr[f]; a0 += xv * w0[f]; a1 += xv * w1[f]; }
        hb[idx] = bfround(a0) | (bfround(a1) << 16);
    } else {
        int idx = (bid - 448 - 12500) * 256 + threadIdx.x;
        int el = idx >> 3, f2 = idx & 7;
        if (f2 >= 7) return;
        float2 v = *(const float2*)(ea + (size_t)eid[el] * EDGE_F + 2 * f2);
        half2_t hh;
        hh[0] = (_Float16)v.x;
        hh[1] = (_Float16)v.y;
        ea_h[(size_t)el * 7 + f2] = __builtin_bit_cast(uint, hh);
    }
}

// ----------------------------- CSR construction ----------------------------
__global__ __launch_bounds__(256)
void hist_kernel(const int* __restrict__ ei, int* __restrict__ deg)
{
    int e = blockIdx.x * 256 + threadIdx.x;
    if (e < NE) atomicAdd(&deg[ei[NE + e]], 1);
}

__global__ __launch_bounds__(256)
void scan1_kernel(const int* __restrict__ deg, int* __restrict__ incl, int* __restrict__ bsum)
{
    int i = blockIdx.x * 256 + threadIdx.x;
    int v = (i < NN) ? deg[i] : 0;
    int lane = threadIdx.x & 63;
#pragma unroll
    for (int off = 1; off < 64; off <<= 1) {
        int u = __shfl_up(v, off);
        if (lane >= off) v += u;
    }
    __shared__ int wsum[4];
    if (lane == 63) wsum[threadIdx.x >> 6] = v;
    __syncthreads();
    int wid = threadIdx.x >> 6;
    int add = 0;
#pragma unroll
    for (int w = 0; w < 3; ++w) if (w < wid) add += wsum[w];
    v += add;
    if (i < NN) incl[i] = v;
    if (threadIdx.x == 255) bsum[blockIdx.x] = v;
}

__global__ __launch_bounds__(256)
void scan2_kernel(const int* __restrict__ bsum, int* __restrict__ bscan, int nb)
{
    int i = threadIdx.x;
    int v = (i < nb) ? bsum[i] : 0;
    int lane = i & 63;
#pragma unroll
    for (int off = 1; off < 64; off <<= 1) {
        int u = __shfl_up(v, off);
        if (lane >= off) v += u;
    }
    __shared__ int wsum[4];
    if (lane == 63) wsum[i >> 6] = v;
    __syncthreads();
    int wid = i >> 6;
    int add = 0;
#pragma unroll
    for (int w = 0; w < 3; ++w) if (w < wid) add += wsum[w];
    v += add;
    bscan[i] = v;
}

__global__ __launch_bounds__(256)
void scan3_kernel(const int* __restrict__ deg, const int* __restrict__ incl,
                  const int* __restrict__ bscan, int* __restrict__ row_start,
                  int* __restrict__ cursor)
{
    int i = blockIdx.x * 256 + threadIdx.x;
    if (i >= NN) return;
    int b = blockIdx.x;
    int base = (b > 0) ? bscan[b - 1] : 0;
    int rs = base + incl[i] - deg[i];
    row_start[i] = rs;
    cursor[i] = rs;
    if (i == 0) row_start[NN] = NE;
}

__global__ __launch_bounds__(256)
void scatter_kernel(const int* __restrict__ ei, int* __restrict__ cursor,
                    int* __restrict__ srcs, int* __restrict__ eid)
{
    int e = blockIdx.x * 256 + threadIdx.x;
    if (e >= NE) return;
    int s = ei[e], d = ei[NE + e];
    int pos = atomicAdd(&cursor[d], 1);
    srcs[pos] = s;
    eid[pos] = e;
}

// --- agg: zin_b[n] = bf16(hb[n] + sum_j relu(hb[src_j] + f16dot(ea_h[j]))) --
#define EMSGH(HV, EP)                                                       \
    {                                                                       \
        float ax = bx, ay = by;                                             \
        _Pragma("unroll")                                                   \
        for (int f = 0; f < 7; ++f) {                                       \
            half2_t av = u2h2((EP)[f]);                                     \
            ax = dot2f(av, w0h[f], ax);                                     \
            ay = dot2f(av, w1h[f], ay);                                     \
        }                                                                   \
        float hx = __uint_as_float((HV) << 16);                             \
        float hy = __uint_as_float((HV) & 0xffff0000u);                     \
        accx += fmaxf(hx + ax, 0.f);                                        \
        accy += fmaxf(hy + ay, 0.f);                                        \
    }

__global__ __launch_bounds__(256)
void agg_f16_kernel(const uint* __restrict__ hb,
                    const int* __restrict__ srcs, const int* __restrict__ row_start,
                    const uint* __restrict__ ea_h, const float* __restrict__ eW,
                    const float* __restrict__ eb, uint* __restrict__ zin_b)
{
    int node = blockIdx.x * 4 + (threadIdx.x >> 6);
    if (node >= NN) return;
    int lane = threadIdx.x & 63;
    int c2 = lane * 2;
    const float4* wp = (const float4*)(eW + lane * 28);
    float4 q0 = wp[0], q1 = wp[1], q2 = wp[2], q3 = wp[3], q4 = wp[4], q5 = wp[5], q6 = wp[6];
    half2_t w0h[7], w1h[7];
    w0h[0][0]=(_Float16)q0.x; w0h[0][1]=(_Float16)q0.y;
    w0h[1][0]=(_Float16)q0.z; w0h[1][1]=(_Float16)q0.w;
    w0h[2][0]=(_Float16)q1.x; w0h[2][1]=(_Float16)q1.y;
    w0h[3][0]=(_Float16)q1.z; w0h[3][1]=(_Float16)q1.w;
    w0h[4][0]=(_Float16)q2.x; w0h[4][1]=(_Float16)q2.y;
    w0h[5][0]=(_Float16)q2.z; w0h[5][1]=(_Float16)q2.w;
    w0h[6][0]=(_Float16)q3.x; w0h[6][1]=(_Float16)q3.y;
    w1h[0][0]=(_Float16)q3.z; w1h[0][1]=(_Float16)q3.w;
    w1h[1][0]=(_Float16)q4.x; w1h[1][1]=(_Float16)q4.y;
    w1h[2][0]=(_Float16)q4.z; w1h[2][1]=(_Float16)q4.w;
    w1h[3][0]=(_Float16)q5.x; w1h[3][1]=(_Float16)q5.y;
    w1h[4][0]=(_Float16)q5.z; w1h[4][1]=(_Float16)q5.w;
    w1h[5][0]=(_Float16)q6.x; w1h[5][1]=(_Float16)q6.y;
    w1h[6][0]=(_Float16)q6.z; w1h[6][1]=(_Float16)q6.w;
    float bx = eb[c2], by = eb[c2 + 1];
    float accx = 0.f, accy = 0.f;
    int beg = __builtin_amdgcn_readfirstlane(row_start[node]);
    int end = __builtin_amdgcn_readfirstlane(row_start[node + 1]);
    int j = beg;
    for (; j + 8 <= end; j += 8) {
        int s[8];
        uint hv[8];
#pragma unroll
        for (int q = 0; q < 8; ++q) s[q] = srcs[j + q];
#pragma unroll
        for (int q = 0; q < 8; ++q) hv[q] = hb[(size_t)s[q] * 64 + lane];
        const uint* e0 = ea_h + (size_t)j * 7;
        EMSGH(hv[0], e0);      EMSGH(hv[1], e0 + 7);
        EMSGH(hv[2], e0 + 14); EMSGH(hv[3], e0 + 21);
        EMSGH(hv[4], e0 + 28); EMSGH(hv[5], e0 + 35);
        EMSGH(hv[6], e0 + 42); EMSGH(hv[7], e0 + 49);
    }
    for (; j + 4 <= end; j += 4) {
        int s0 = srcs[j], s1 = srcs[j + 1], s2 = srcs[j + 2], s3 = srcs[j + 3];
        uint hv0 = hb[(size_t)s0 * 64 + lane];
        uint hv1 = hb[(size_t)s1 * 64 + lane];
        uint hv2 = hb[(size_t)s2 * 64 + lane];
        uint hv3 = hb[(size_t)s3 * 64 + lane];
        const uint* e0 = ea_h + (size_t)j * 7;
        EMSGH(hv0, e0);      EMSGH(hv1, e0 + 7);
        EMSGH(hv2, e0 + 14); EMSGH(hv3, e0 + 21);
    }
    for (; j < end; ++j) {
        uint hv0 = hb[(size_t)srcs[j] * 64 + lane];
        const uint* e0 = ea_h + (size_t)j * 7;
        EMSGH(hv0, e0);
    }
    uint hself = hb[(size_t)node * 64 + lane];
    accx += __uint_as_float(hself << 16);
    accy += __uint_as_float(hself & 0xffff0000u);
    zin_b[(size_t)node * 64 + lane] = bfround(accx) | (bfround(accy) << 16);
}

// --------- fused layer: hb = bf16(relu(relu(BN(zin@W1^T+b1))@W2^T+b2) + hb) --
// zin_b is packed bf16 (2ch/uint); staging = swizzled copy. In-place hb safe.
__global__ __launch_bounds__(256)
void fused_layer_kernel(const uint* __restrict__ zin_b,
                        const ushort* __restrict__ w1b, const float* __restrict__ b1,
                        const float* __restrict__ gamma, const float* __restrict__ beta,
                        const float* __restrict__ mean, const float* __restrict__ var,
                        const ushort* __restrict__ w2b, const float* __restrict__ b2,
                        ushort* __restrict__ hb, int n)
{
    __shared__ uint Ahi[64 * 64];  // bf16[64][128], XOR-swizzled; reused for z
    const int t = threadIdx.x;
    const int nb = blockIdx.x * 64;

    // ---- stage zin_b: pure swizzled copy, 16 uints (32 ch) per thread ----
    {
        int row = t >> 2;
        int kq = (t & 3) * 16;       // uint index within row (64 uints/row)
        int gn = nb + row;
        uint vals[16];
        if (gn < n) {
            const uint4* src = (const uint4*)(zin_b + (size_t)gn * 64 + kq);
#pragma unroll
            for (int i = 0; i < 4; ++i) {
                uint4 v = src[i];
                vals[4 * i] = v.x; vals[4 * i + 1] = v.y; vals[4 * i + 2] = v.z; vals[4 * i + 3] = v.w;
            }
        } else {
#pragma unroll
            for (int i = 0; i < 16; ++i) vals[i] = 0;
        }
        uint rowbase = row * 256;
#pragma unroll
        for (int i = 0; i < 4; ++i) {
            uint byte = (rowbase + (kq + 4 * i) * 4) ^ ((row & 7) << 4);
            *(uint4*)((char*)Ahi + byte) = make_uint4(vals[4 * i], vals[4 * i + 1], vals[4 * i + 2], vals[4 * i + 3]);
        }
    }

    const int w  = t >> 6, l = t & 63;
    const int lc = l & 15, lk = l >> 4;
    bf16x8 wf1[2][4], wf2[2][4];
#pragma unroll
    for (int ct = 0; ct < 2; ++ct)
#pragma unroll
        for (int ks = 0; ks < 4; ++ks) {
            size_t off = (size_t)(w * 32 + ct * 16 + lc) * HD + ks * 32 + lk * 8;
            wf1[ct][ks] = *(const bf16x8*)(w1b + off);
            wf2[ct][ks] = *(const bf16x8*)(w2b + off);
        }

    __syncthreads();

    // ---- GEMM1: single bf16 ----
    f32x4 acc[4][2];
#pragma unroll
    for (int rt = 0; rt < 4; ++rt)
#pragma unroll
        for (int ct = 0; ct < 2; ++ct) acc[rt][ct] = (f32x4){0.f, 0.f, 0.f, 0.f};

#pragma unroll
    for (int ks = 0; ks < 4; ++ks) {
#pragma unroll
        for (int rt = 0; rt < 4; ++rt) {
            int row = rt * 16 + lc;
            uint byte = ((uint)(row * 256 + (ks * 32 + lk * 8) * 2)) ^ ((row & 7) << 4);
            bf16x8 ah = *(const bf16x8*)((char*)Ahi + byte);
            acc[rt][0] = __builtin_amdgcn_mfma_f32_16x16x32_bf16(ah, wf1[0][ks], acc[rt][0], 0, 0, 0);
            acc[rt][1] = __builtin_amdgcn_mfma_f32_16x16x32_bf16(ah, wf1[1][ks], acc[rt][1], 0, 0, 0);
        }
    }

    __syncthreads();

    // ---- epilogue1: BN + relu -> z bf16 into Ahi ----
#pragma unroll
    for (int ct = 0; ct < 2; ++ct) {
        int col = w * 32 + ct * 16 + lc;
        float bi = b1[col];
        float scv = gamma[col] * rsqrtf(var[col] + BN_EPS);
        float shv = beta[col] - mean[col] * scv;
#pragma unroll
        for (int rt = 0; rt < 4; ++rt) {
#pragma unroll
            for (int r = 0; r < 4; ++r) {
                int rowl = rt * 16 + lk * 4 + r;
                float v = (acc[rt][ct][r] + bi) * scv + shv;
                v = fmaxf(v, 0.f);
                uint byte = ((uint)(rowl * 256 + col * 2)) ^ ((rowl & 7) << 4);
                *(ushort*)((char*)Ahi + byte) = (ushort)bfround(v);
            }
        }
    }

    __syncthreads();

    // ---- GEMM2: single bf16 ----
    f32x4 acc2[4][2];
#pragma unroll
    for (int rt = 0; rt < 4; ++rt)
#pragma unroll
        for (int ct = 0; ct < 2; ++ct) acc2[rt][ct] = (f32x4){0.f, 0.f, 0.f, 0.f};

#pragma unroll
    for (int ks = 0; ks < 4; ++ks) {
#pragma unroll
        for (int rt = 0; rt < 4; ++rt) {
            int row = rt * 16 + lc;
            uint byte = ((uint)(row * 256 + (ks * 32 + lk * 8) * 2)) ^ ((row & 7) << 4);
            bf16x8 az = *(const bf16x8*)((char*)Ahi + byte);
            acc2[rt][0] = __builtin_amdgcn_mfma_f32_16x16x32_bf16(az, wf2[0][ks], acc2[rt][0], 0, 0, 0);
            acc2[rt][1] = __builtin_amdgcn_mfma_f32_16x16x32_bf16(az, wf2[1][ks], acc2[rt][1], 0, 0, 0);
        }
    }

    // ---- epilogue2: relu + bf16 residual; write hb ----
#pragma unroll
    for (int ct = 0; ct < 2; ++ct) {
        int col = w * 32 + ct * 16 + lc;
        float bi = b2[col];
#pragma unroll
        for (int rt = 0; rt < 4; ++rt) {
#pragma unroll
            for (int r = 0; r < 4; ++r) {
                int row = nb + rt * 16 + lk * 4 + r;
                if (row < n) {
                    float hprev = __uint_as_float(((uint)hb[(size_t)row * HD + col]) << 16);
                    float v = fmaxf(acc2[rt][ct][r] + bi, 0.f) + hprev;
                    hb[(size_t)row * HD + col] = (ushort)bfround(v);
                }
            }
        }
    }
}

// -------- pooling over bf16 h: chunked local sums, rare atomics ----
__global__ __launch_bounds__(128)
void pool_kernel(const ushort* __restrict__ hb, const int* __restrict__ batch,
                 float* __restrict__ pooled, int* __restrict__ counts, int n, int chunk)
{
    int c = threadIdx.x;
    int n_start = blockIdx.x * chunk;
    if (n_start >= n) return;
    int n_end = min(n_start + chunk, n);
    float local = 0.f;
    int cnt = 0;
    int g_cur = batch[n_start];
    for (int nd = n_start; nd < n_end; ++nd) {
        int g = batch[nd];
        if (g != g_cur) {
            atomicAdd(&pooled[g_cur * HD + c], local);
            if (c == 0) atomicAdd(&counts[g_cur], cnt);
            local = 0.f; cnt = 0; g_cur = g;
        }
        local += __uint_as_float(((uint)hb[(size_t)nd * HD + c]) << 16);
        cnt++;
    }
    atomicAdd(&pooled[g_cur * HD + c], local);
    if (c == 0) atomicAdd(&counts[g_cur], cnt);
}

__global__ __launch_bounds__(128)
void final_kernel(const float* __restrict__ pooled, const int* __restrict__ counts,
                  const float* __restrict__ projT, const float* __restrict__ pb,
                  float* __restrict__ out)
{
    __shared__ float p_lds[HD];
    int g = blockIdx.x, p = threadIdx.x;
    float inv = 1.f / fmaxf((float)counts[g], 1.f);
    p_lds[p] = pooled[g * HD + p];
    __syncthreads();
    float acc = 0.f;
#pragma unroll 4
    for (int c = 0; c < HD; ++c) acc += p_lds[c] * projT[c * HD + p];
    out[g * HD + p] = acc * inv + pb[p];
}

extern "C" void kernel_launch(void* const* d_in, const int* in_sizes, int n_in,
                              void* d_out, int out_size, void* d_ws, size_t ws_size,
                              hipStream_t stream)
{
    const float* x        = (const float*)d_in[0];
    const int*   edge_idx = (const int*)d_in[1];
    const float* edge_attr= (const float*)d_in[2];
    const int*   batch    = (const int*)d_in[3];
    const float* node_W   = (const float*)d_in[4];
    const float* node_b   = (const float*)d_in[5];
    const float* edge_W   = (const float*)d_in[6];
    const float* edge_b   = (const float*)d_in[7];
    const float* lin1_b   = (const float*)d_in[9];
    const float* bn_gamma = (const float*)d_in[10];
    const float* bn_beta  = (const float*)d_in[11];
    const float* bn_mean  = (const float*)d_in[12];
    const float* bn_var   = (const float*)d_in[13];
    const float* lin2_b   = (const float*)d_in[15];
    const float* proj_b   = (const float*)d_in[17];

    char* ws = (char*)d_ws;
    uint*   hb       = (uint*)  (ws);                  // 12.8 MB (bf16 packed)
    uint*   zin_b    = (uint*)  (ws + 12800000);       // 12.8 MB (bf16 packed)
    uint*   ea_h     = (uint*)  (ws + 25600000);       // 22.4 MB
    int*    srcs     = (int*)   (ws + 48000000);       // 3.2 MB
    int*    eid      = (int*)   (ws + 51200000);       // 3.2 MB
    ushort* wb       = (ushort*)(ws + 54400000);       // 196,608
    float*  projT    = (float*) (ws + 54600000);       // 65,536
    float*  pooled   = (float*) (ws + 54700000);       // 32,768
    int*    counts   = (int*)   (ws + 54732768);       // 256
    int*    deg      = (int*)   (ws + 54740000);       // 200,000
    int*    incl     = (int*)   (ws + 54940000);       // 200,000
    int*    bsum     = (int*)   (ws + 55140000);       // 1,024
    int*    bscan    = (int*)   (ws + 55142048);       // 1,024
    int*    row_start= (int*)   (ws + 55144096);       // 200,064
    int*    cursor   = (int*)   (ws + 55344160);       // 200,000

    const int NB = (NN + 255) / 256;  // 196

    // --- CSR build (edge_index constant across layers) ---
    hipMemsetAsync(deg, 0, NN * sizeof(int), stream);
    hist_kernel<<<(NE + 255) / 256, 256, 0, stream>>>(edge_idx, deg);
    scan1_kernel<<<NB, 256, 0, stream>>>(deg, incl, bsum);
    scan2_kernel<<<1, 256, 0, stream>>>(bsum, bscan, NB);
    scan3_kernel<<<NB, 256, 0, stream>>>(deg, incl, bscan, row_start, cursor);
    scatter_kernel<<<(NE + 255) / 256, 256, 0, stream>>>(edge_idx, cursor, srcs, eid);

    // --- init: weights + node embed (hb) + ea f16 permute ---
    init_kernel<<<448 + 12500 + 25000, 256, 0, stream>>>(
        x, node_W, node_b, (const float*)d_in[8], (const float*)d_in[14],
        (const float*)d_in[16], edge_attr, eid, hb, ea_h, wb, projT);

    for (int i = 0; i < NL; ++i) {
        agg_f16_kernel<<<(NN + 3) / 4, 256, 0, stream>>>(
            hb, srcs, row_start, ea_h, edge_W, edge_b, zin_b);
        fused_layer_kernel<<<(NN + 63) / 64, 256, 0, stream>>>(
            zin_b, wb + (size_t)i * HD * HD, lin1_b + i * HD,
            bn_gamma + i * HD, bn_beta + i * HD, bn_mean + i * HD, bn_var + i * HD,
            wb + (size_t)(3 + i) * HD * HD, lin2_b + i * HD,
            (ushort*)hb, NN);
    }

    hipMemsetAsync(pooled, 0, NG * HD * sizeof(float) + NG * sizeof(int) + 4000, stream);
    pool_kernel<<<(NN + 31) / 32, 128, 0, stream>>>((const ushort*)hb, batch, pooled, counts, NN, 32);
    final_kernel<<<NG, HD, 0, stream>>>(pooled, counts, projT, proj_b, (float*)d_out);
}

// Round 15
// 403.801 us; speedup vs baseline: 1.5354x; 1.0226x over previous
//
#include <hip/hip_runtime.h>

typedef unsigned int uint;
typedef unsigned short ushort;
typedef __attribute__((ext_vector_type(8))) short bf16x8;
typedef __attribute__((ext_vector_type(4))) float f32x4;
typedef __attribute__((ext_vector_type(2))) _Float16 half2_t;

#define NN 50000
#define NE 800000
#define NG 64
#define NODE_F 11
#define EDGE_F 14
#define HD 128
#define NL 3
#define BN_EPS 1e-5f

#if defined(__has_builtin)
#if __has_builtin(__builtin_amdgcn_fdot2)
#define HAS_DOT2 1
#endif
#endif

__device__ __forceinline__ uint bfround(float v) {
    uint b = __float_as_uint(v);
    return (b + 0x7fffu + ((b >> 16) & 1u)) >> 16;
}

__device__ __forceinline__ float dot2f(half2_t a, half2_t b, float acc) {
#ifdef HAS_DOT2
    return __builtin_amdgcn_fdot2(a, b, acc, false);
#else
    return acc + (float)a[0] * (float)b[0] + (float)a[1] * (float)b[1];
#endif
}

__device__ __forceinline__ half2_t u2h2(uint u) {
    return __builtin_bit_cast(half2_t, u);
}

// --- init: weights (blks<448) + node embed (12500) + ea f16 permute (25000) + srcs copy (3125)
__global__ __launch_bounds__(256)
void init_kernel(const float* __restrict__ x, const float* __restrict__ nW,
                 const float* __restrict__ nb_, const float* __restrict__ lin1,
                 const float* __restrict__ lin2, const float* __restrict__ proj,
                 const float* __restrict__ ea, const int2* __restrict__ pairs,
                 uint* __restrict__ hb, uint* __restrict__ ea_h,
                 int* __restrict__ srcs, ushort* __restrict__ wb,
                 float* __restrict__ projT)
{
    int bid = blockIdx.x;
    if (bid < 448) {
        int idx = bid * 256 + threadIdx.x;
        if (idx < 6 * HD * HD) {
            int m = idx >> 14, e = idx & (HD * HD - 1);
            const float* src = (m < 3) ? (lin1 + m * HD * HD) : (lin2 + (m - 3) * HD * HD);
            wb[idx] = (ushort)bfround(src[e]);
        } else if (idx < 7 * HD * HD) {
            int e = idx - 6 * HD * HD;
            int r = e >> 7, c = e & 127;
            projT[c * HD + r] = proj[r * HD + c];
        }
    } else if (bid < 448 + 12500) {
        uint idx = (uint)(bid - 448) * 256u + threadIdx.x;
        uint node = idx >> 6, cp = idx & 63u;
        uint c2 = cp * 2u;
        const float* xr = x + node * NODE_F;
        const float* w0 = nW + c2 * NODE_F;
        const float* w1 = w0 + NODE_F;
        float a0 = nb_[c2], a1 = nb_[c2 + 1];
#pragma unroll
        for (int f = 0; f < NODE_F; ++f) { float xv = xr[f]; a0 += xv * w0[f]; a1 += xv * w1[f]; }
        hb[idx] = bfround(a0) | (bfround(a1) << 16);
    } else if (bid < 448 + 12500 + 25000) {
        uint idx = (uint)(bid - 448 - 12500) * 256u + threadIdx.x;
        uint el = idx >> 3, f2 = idx & 7u;
        if (f2 >= 7u) return;
        float2 v = *(const float2*)(ea + (size_t)pairs[el].y * EDGE_F + 2 * f2);
        half2_t hh;
        hh[0] = (_Float16)v.x;
        hh[1] = (_Float16)v.y;
        ea_h[el * 7u + f2] = __builtin_bit_cast(uint, hh);
    } else {
        uint i = (uint)(bid - 448 - 12500 - 25000) * 256u + threadIdx.x;
        if (i < NE) srcs[i] = pairs[i].x;
    }
}

// ----------------------------- CSR construction ----------------------------
__global__ __launch_bounds__(256)
void hist_kernel(const int* __restrict__ ei, int* __restrict__ deg)
{
    int e = blockIdx.x * 256 + threadIdx.x;
    if (e < NE) atomicAdd(&deg[ei[NE + e]], 1);
}

__global__ __launch_bounds__(256)
void scan1_kernel(const int* __restrict__ deg, int* __restrict__ incl, int* __restrict__ bsum)
{
    int i = blockIdx.x * 256 + threadIdx.x;
    int v = (i < NN) ? deg[i] : 0;
    int lane = threadIdx.x & 63;
#pragma unroll
    for (int off = 1; off < 64; off <<= 1) {
        int u = __shfl_up(v, off);
        if (lane >= off) v += u;
    }
    __shared__ int wsum[4];
    if (lane == 63) wsum[threadIdx.x >> 6] = v;
    __syncthreads();
    int wid = threadIdx.x >> 6;
    int add = 0;
#pragma unroll
    for (int w = 0; w < 3; ++w) if (w < wid) add += wsum[w];
    v += add;
    if (i < NN) incl[i] = v;
    if (threadIdx.x == 255) bsum[blockIdx.x] = v;
}

__global__ __launch_bounds__(256)
void scan2_kernel(const int* __restrict__ bsum, int* __restrict__ bscan, int nb)
{
    int i = threadIdx.x;
    int v = (i < nb) ? bsum[i] : 0;
    int lane = i & 63;
#pragma unroll
    for (int off = 1; off < 64; off <<= 1) {
        int u = __shfl_up(v, off);
        if (lane >= off) v += u;
    }
    __shared__ int wsum[4];
    if (lane == 63) wsum[i >> 6] = v;
    __syncthreads();
    int wid = i >> 6;
    int add = 0;
#pragma unroll
    for (int w = 0; w < 3; ++w) if (w < wid) add += wsum[w];
    v += add;
    bscan[i] = v;
}

__global__ __launch_bounds__(256)
void scan3_kernel(const int* __restrict__ deg, const int* __restrict__ incl,
                  const int* __restrict__ bscan, int* __restrict__ row_start,
                  int* __restrict__ cursor)
{
    int i = blockIdx.x * 256 + threadIdx.x;
    if (i >= NN) return;
    int b = blockIdx.x;
    int base = (b > 0) ? bscan[b - 1] : 0;
    int rs = base + incl[i] - deg[i];
    row_start[i] = rs;
    cursor[i] = rs;
    if (i == 0) row_start[NN] = NE;
}

__global__ __launch_bounds__(256)
void scatter_kernel(const int* __restrict__ ei, int* __restrict__ cursor,
                    int2* __restrict__ pairs)
{
    int e = blockIdx.x * 256 + threadIdx.x;
    if (e >= NE) return;
    int s = ei[e], d = ei[NE + e];
    int pos = atomicAdd(&cursor[d], 1);
    pairs[pos] = make_int2(s, e);
}

// --- agg: zin_b[n] = bf16(hb[n] + sum_j relu(hb[src_j] + f16dot(ea_h[j]))) --
// uint offsets -> saddr-form gathers (SGPR base + 32b voffset).
#define EMSGH(HV, EP)                                                       \
    {                                                                       \
        float ax = bx, ay = by;                                             \
        _Pragma("unroll")                                                   \
        for (int f = 0; f < 7; ++f) {                                       \
            half2_t av = u2h2((EP)[f]);                                     \
            ax = dot2f(av, w0h[f], ax);                                     \
            ay = dot2f(av, w1h[f], ay);                                     \
        }                                                                   \
        float hx = __uint_as_float((HV) << 16);                             \
        float hy = __uint_as_float((HV) & 0xffff0000u);                     \
        accx += fmaxf(hx + ax, 0.f);                                        \
        accy += fmaxf(hy + ay, 0.f);                                        \
    }

__global__ __launch_bounds__(256)
void agg_f16_kernel(const uint* __restrict__ hb,
                    const int* __restrict__ srcs, const int* __restrict__ row_start,
                    const uint* __restrict__ ea_h, const float* __restrict__ eW,
                    const float* __restrict__ eb, uint* __restrict__ zin_b)
{
    uint node = blockIdx.x * 4u + (threadIdx.x >> 6);
    if (node >= NN) return;
    uint lane = threadIdx.x & 63u;
    uint c2 = lane * 2u;
    const float4* wp = (const float4*)(eW + lane * 28u);
    float4 q0 = wp[0], q1 = wp[1], q2 = wp[2], q3 = wp[3], q4 = wp[4], q5 = wp[5], q6 = wp[6];
    half2_t w0h[7], w1h[7];
    w0h[0][0]=(_Float16)q0.x; w0h[0][1]=(_Float16)q0.y;
    w0h[1][0]=(_Float16)q0.z; w0h[1][1]=(_Float16)q0.w;
    w0h[2][0]=(_Float16)q1.x; w0h[2][1]=(_Float16)q1.y;
    w0h[3][0]=(_Float16)q1.z; w0h[3][1]=(_Float16)q1.w;
    w0h[4][0]=(_Float16)q2.x; w0h[4][1]=(_Float16)q2.y;
    w0h[5][0]=(_Float16)q2.z; w0h[5][1]=(_Float16)q2.w;
    w0h[6][0]=(_Float16)q3.x; w0h[6][1]=(_Float16)q3.y;
    w1h[0][0]=(_Float16)q3.z; w1h[0][1]=(_Float16)q3.w;
    w1h[1][0]=(_Float16)q4.x; w1h[1][1]=(_Float16)q4.y;
    w1h[2][0]=(_Float16)q4.z; w1h[2][1]=(_Float16)q4.w;
    w1h[3][0]=(_Float16)q5.x; w1h[3][1]=(_Float16)q5.y;
    w1h[4][0]=(_Float16)q5.z; w1h[4][1]=(_Float16)q5.w;
    w1h[5][0]=(_Float16)q6.x; w1h[5][1]=(_Float16)q6.y;
    w1h[6][0]=(_Float16)q6.z; w1h[6][1]=(_Float16)q6.w;
    float bx = eb[c2], by = eb[c2 + 1];
    float accx = 0.f, accy = 0.f;
    int beg = __builtin_amdgcn_readfirstlane(row_start[node]);
    int end = __builtin_amdgcn_readfirstlane(row_start[node + 1]);
    int j = beg;
    for (; j + 8 <= end; j += 8) {
        uint s[8];
        uint hv[8];
#pragma unroll
        for (int q = 0; q < 8; ++q) s[q] = (uint)srcs[(uint)j + q];
#pragma unroll
        for (int q = 0; q < 8; ++q) hv[q] = hb[s[q] * 64u + lane];
        const uint* e0 = ea_h + (uint)j * 7u;
        EMSGH(hv[0], e0);      EMSGH(hv[1], e0 + 7);
        EMSGH(hv[2], e0 + 14); EMSGH(hv[3], e0 + 21);
        EMSGH(hv[4], e0 + 28); EMSGH(hv[5], e0 + 35);
        EMSGH(hv[6], e0 + 42); EMSGH(hv[7], e0 + 49);
    }
    for (; j + 4 <= end; j += 4) {
        uint s0 = (uint)srcs[(uint)j], s1 = (uint)srcs[(uint)j + 1];
        uint s2 = (uint)srcs[(uint)j + 2], s3 = (uint)srcs[(uint)j + 3];
        uint hv0 = hb[s0 * 64u + lane];
        uint hv1 = hb[s1 * 64u + lane];
        uint hv2 = hb[s2 * 64u + lane];
        uint hv3 = hb[s3 * 64u + lane];
        const uint* e0 = ea_h + (uint)j * 7u;
        EMSGH(hv0, e0);      EMSGH(hv1, e0 + 7);
        EMSGH(hv2, e0 + 14); EMSGH(hv3, e0 + 21);
    }
    for (; j < end; ++j) {
        uint hv0 = hb[(uint)srcs[(uint)j] * 64u + lane];
        const uint* e0 = ea_h + (uint)j * 7u;
        EMSGH(hv0, e0);
    }
    uint hself = hb[node * 64u + lane];
    accx += __uint_as_float(hself << 16);
    accy += __uint_as_float(hself & 0xffff0000u);
    zin_b[node * 64u + lane] = bfround(accx) | (bfround(accy) << 16);
}

// --------- fused layer: hb = bf16(relu(relu(BN(zin@W1^T+b1))@W2^T+b2) + hb) --
__global__ __launch_bounds__(256)
void fused_layer_kernel(const uint* __restrict__ zin_b,
                        const ushort* __restrict__ w1b, const float* __restrict__ b1,
                        const float* __restrict__ gamma, const float* __restrict__ beta,
                        const float* __restrict__ mean, const float* __restrict__ var,
                        const ushort* __restrict__ w2b, const float* __restrict__ b2,
                        ushort* __restrict__ hb, int n)
{
    __shared__ uint Ahi[64 * 64];  // bf16[64][128], XOR-swizzled; reused for z
    const int t = threadIdx.x;
    const int nb = blockIdx.x * 64;

    {
        int row = t >> 2;
        int kq = (t & 3) * 16;
        int gn = nb + row;
        uint vals[16];
        if (gn < n) {
            const uint4* src = (const uint4*)(zin_b + (size_t)gn * 64 + kq);
#pragma unroll
            for (int i = 0; i < 4; ++i) {
                uint4 v = src[i];
                vals[4 * i] = v.x; vals[4 * i + 1] = v.y; vals[4 * i + 2] = v.z; vals[4 * i + 3] = v.w;
            }
        } else {
#pragma unroll
            for (int i = 0; i < 16; ++i) vals[i] = 0;
        }
        uint rowbase = row * 256;
#pragma unroll
        for (int i = 0; i < 4; ++i) {
            uint byte = (rowbase + (kq + 4 * i) * 4) ^ ((row & 7) << 4);
            *(uint4*)((char*)Ahi + byte) = make_uint4(vals[4 * i], vals[4 * i + 1], vals[4 * i + 2], vals[4 * i + 3]);
        }
    }

    const int w  = t >> 6, l = t & 63;
    const int lc = l & 15, lk = l >> 4;
    bf16x8 wf1[2][4], wf2[2][4];
#pragma unroll
    for (int ct = 0; ct < 2; ++ct)
#pragma unroll
        for (int ks = 0; ks < 4; ++ks) {
            size_t off = (size_t)(w * 32 + ct * 16 + lc) * HD + ks * 32 + lk * 8;
            wf1[ct][ks] = *(const bf16x8*)(w1b + off);
            wf2[ct][ks] = *(const bf16x8*)(w2b + off);
        }

    __syncthreads();

    f32x4 acc[4][2];
#pragma unroll
    for (int rt = 0; rt < 4; ++rt)
#pragma unroll
        for (int ct = 0; ct < 2; ++ct) acc[rt][ct] = (f32x4){0.f, 0.f, 0.f, 0.f};

#pragma unroll
    for (int ks = 0; ks < 4; ++ks) {
#pragma unroll
        for (int rt = 0; rt < 4; ++rt) {
            int row = rt * 16 + lc;
            uint byte = ((uint)(row * 256 + (ks * 32 + lk * 8) * 2)) ^ ((row & 7) << 4);
            bf16x8 ah = *(const bf16x8*)((char*)Ahi + byte);
            acc[rt][0] = __builtin_amdgcn_mfma_f32_16x16x32_bf16(ah, wf1[0][ks], acc[rt][0], 0, 0, 0);
            acc[rt][1] = __builtin_amdgcn_mfma_f32_16x16x32_bf16(ah, wf1[1][ks], acc[rt][1], 0, 0, 0);
        }
    }

    __syncthreads();

#pragma unroll
    for (int ct = 0; ct < 2; ++ct) {
        int col = w * 32 + ct * 16 + lc;
        float bi = b1[col];
        float scv = gamma[col] * rsqrtf(var[col] + BN_EPS);
        float shv = beta[col] - mean[col] * scv;
#pragma unroll
        for (int rt = 0; rt < 4; ++rt) {
#pragma unroll
            for (int r = 0; r < 4; ++r) {
                int rowl = rt * 16 + lk * 4 + r;
                float v = (acc[rt][ct][r] + bi) * scv + shv;
                v = fmaxf(v, 0.f);
                uint byte = ((uint)(rowl * 256 + col * 2)) ^ ((rowl & 7) << 4);
                *(ushort*)((char*)Ahi + byte) = (ushort)bfround(v);
            }
        }
    }

    __syncthreads();

    f32x4 acc2[4][2];
#pragma unroll
    for (int rt = 0; rt < 4; ++rt)
#pragma unroll
        for (int ct = 0; ct < 2; ++ct) acc2[rt][ct] = (f32x4){0.f, 0.f, 0.f, 0.f};

#pragma unroll
    for (int ks = 0; ks < 4; ++ks) {
#pragma unroll
        for (int rt = 0; rt < 4; ++rt) {
            int row = rt * 16 + lc;
            uint byte = ((uint)(row * 256 + (ks * 32 + lk * 8) * 2)) ^ ((row & 7) << 4);
            bf16x8 az = *(const bf16x8*)((char*)Ahi + byte);
            acc2[rt][0] = __builtin_amdgcn_mfma_f32_16x16x32_bf16(az, wf2[0][ks], acc2[rt][0], 0, 0, 0);
            acc2[rt][1] = __builtin_amdgcn_mfma_f32_16x16x32_bf16(az, wf2[1][ks], acc2[rt][1], 0, 0, 0);
        }
    }

#pragma unroll
    for (int ct = 0; ct < 2; ++ct) {
        int col = w * 32 + ct * 16 + lc;
        float bi = b2[col];
#pragma unroll
        for (int rt = 0; rt < 4; ++rt) {
#pragma unroll
            for (int r = 0; r < 4; ++r) {
                int row = nb + rt * 16 + lk * 4 + r;
                if (row < n) {
                    float hprev = __uint_as_float(((uint)hb[(size_t)row * HD + col]) << 16);
                    float v = fmaxf(acc2[rt][ct][r] + bi, 0.f) + hprev;
                    hb[(size_t)row * HD + col] = (ushort)bfround(v);
                }
            }
        }
    }
}

// -------- pooling over bf16 h: chunked local sums, rare atomics ----
__global__ __launch_bounds__(128)
void pool_kernel(const ushort* __restrict__ hb, const int* __restrict__ batch,
                 float* __restrict__ pooled, int* __restrict__ counts, int n, int chunk)
{
    int c = threadIdx.x;
    int n_start = blockIdx.x * chunk;
    if (n_start >= n) return;
    int n_end = min(n_start + chunk, n);
    float local = 0.f;
    int cnt = 0;
    int g_cur = batch[n_start];
    for (int nd = n_start; nd < n_end; ++nd) {
        int g = batch[nd];
        if (g != g_cur) {
            atomicAdd(&pooled[g_cur * HD + c], local);
            if (c == 0) atomicAdd(&counts[g_cur], cnt);
            local = 0.f; cnt = 0; g_cur = g;
        }
        local += __uint_as_float(((uint)hb[(size_t)nd * HD + c]) << 16);
        cnt++;
    }
    atomicAdd(&pooled[g_cur * HD + c], local);
    if (c == 0) atomicAdd(&counts[g_cur], cnt);
}

__global__ __launch_bounds__(128)
void final_kernel(const float* __restrict__ pooled, const int* __restrict__ counts,
                  const float* __restrict__ projT, const float* __restrict__ pb,
                  float* __restrict__ out)
{
    __shared__ float p_lds[HD];
    int g = blockIdx.x, p = threadIdx.x;
    float inv = 1.f / fmaxf((float)counts[g], 1.f);
    p_lds[p] = pooled[g * HD + p];
    __syncthreads();
    float acc = 0.f;
#pragma unroll 4
    for (int c = 0; c < HD; ++c) acc += p_lds[c] * projT[c * HD + p];
    out[g * HD + p] = acc * inv + pb[p];
}

extern "C" void kernel_launch(void* const* d_in, const int* in_sizes, int n_in,
                              void* d_out, int out_size, void* d_ws, size_t ws_size,
                              hipStream_t stream)
{
    const float* x        = (const float*)d_in[0];
    const int*   edge_idx = (const int*)d_in[1];
    const float* edge_attr= (const float*)d_in[2];
    const int*   batch    = (const int*)d_in[3];
    const float* node_W   = (const float*)d_in[4];
    const float* node_b   = (const float*)d_in[5];
    const float* edge_W   = (const float*)d_in[6];
    const float* edge_b   = (const float*)d_in[7];
    const float* lin1_b   = (const float*)d_in[9];
    const float* bn_gamma = (const float*)d_in[10];
    const float* bn_beta  = (const float*)d_in[11];
    const float* bn_mean  = (const float*)d_in[12];
    const float* bn_var   = (const float*)d_in[13];
    const float* lin2_b   = (const float*)d_in[15];
    const float* proj_b   = (const float*)d_in[17];

    char* ws = (char*)d_ws;
    uint*   hb       = (uint*)  (ws);                  // 12.8 MB (bf16 packed)
    uint*   zin_b    = (uint*)  (ws + 12800000);       // 12.8 MB (bf16 packed)
    uint*   ea_h     = (uint*)  (ws + 25600000);       // 22.4 MB
    int2*   pairs    = (int2*)  (ws + 48000000);       // 6.4 MB {src, eid}
    int*    srcs     = (int*)   (ws + 54400000);       // 3.2 MB
    ushort* wb       = (ushort*)(ws + 57600000);       // 196,608
    float*  projT    = (float*) (ws + 57800000);       // 65,536
    float*  pooled   = (float*) (ws + 57900000);       // 32,768
    int*    counts   = (int*)   (ws + 57932768);       // 256
    int*    deg      = (int*)   (ws + 57940000);       // 200,000
    int*    incl     = (int*)   (ws + 58140000);       // 200,000
    int*    bsum     = (int*)   (ws + 58340000);       // 1,024
    int*    bscan    = (int*)   (ws + 58342048);       // 1,024
    int*    row_start= (int*)   (ws + 58344096);       // 200,064
    int*    cursor   = (int*)   (ws + 58544160);       // 200,000

    const int NB = (NN + 255) / 256;  // 196

    // --- CSR build (edge_index constant across layers) ---
    hipMemsetAsync(deg, 0, NN * sizeof(int), stream);
    hist_kernel<<<(NE + 255) / 256, 256, 0, stream>>>(edge_idx, deg);
    scan1_kernel<<<NB, 256, 0, stream>>>(deg, incl, bsum);
    scan2_kernel<<<1, 256, 0, stream>>>(bsum, bscan, NB);
    scan3_kernel<<<NB, 256, 0, stream>>>(deg, incl, bscan, row_start, cursor);
    scatter_kernel<<<(NE + 255) / 256, 256, 0, stream>>>(edge_idx, cursor, pairs);

    // --- init: weights + node embed (hb) + ea f16 permute + srcs copy ---
    init_kernel<<<448 + 12500 + 25000 + 3125, 256, 0, stream>>>(
        x, node_W, node_b, (const float*)d_in[8], (const float*)d_in[14],
        (const float*)d_in[16], edge_attr, pairs, hb, ea_h, srcs, wb, projT);

    for (int i = 0; i < NL; ++i) {
        agg_f16_kernel<<<(NN + 3) / 4, 256, 0, stream>>>(
            hb, srcs, row_start, ea_h, edge_W, edge_b, zin_b);
        fused_layer_kernel<<<(NN + 63) / 64, 256, 0, stream>>>(
            zin_b, wb + (size_t)i * HD * HD, lin1_b + i * HD,
            bn_gamma + i * HD, bn_beta + i * HD, bn_mean + i * HD, bn_var + i * HD,
            wb + (size_t)(3 + i) * HD * HD, lin2_b + i * HD,
            (ushort*)hb, NN);
    }

    hipMemsetAsync(pooled, 0, NG * HD * sizeof(float) + NG * sizeof(int) + 4000, stream);
    pool_kernel<<<(NN + 31) / 32, 128, 0, stream>>>((const ushort*)hb, batch, pooled, counts, NN, 32);
    final_kernel<<<NG, HD, 0, stream>>>(pooled, counts, projT, proj_b, (float*)d_out);
}

// Round 16
// 370.514 us; speedup vs baseline: 1.6734x; 1.0898x over previous
//
#include <hip/hip_runtime.h>

typedef unsigned int uint;
typedef unsigned short ushort;
typedef __attribute__((ext_vector_type(8))) short bf16x8;
typedef __attribute__((ext_vector_type(4))) float f32x4;
typedef __attribute__((ext_vector_type(2))) _Float16 half2_t;

#define NN 50000
#define NE 800000
#define NG 64
#define NODE_F 11
#define EDGE_F 14
#define HD 128
#define NL 3
#define BN_EPS 1e-5f

#if defined(__has_builtin)
#if __has_builtin(__builtin_amdgcn_fdot2)
#define HAS_DOT2 1
#endif
#endif

__device__ __forceinline__ uint bfround(float v) {
    uint b = __float_as_uint(v);
    return (b + 0x7fffu + ((b >> 16) & 1u)) >> 16;
}

__device__ __forceinline__ float dot2f(half2_t a, half2_t b, float acc) {
#ifdef HAS_DOT2
    return __builtin_amdgcn_fdot2(a, b, acc, false);
#else
    return acc + (float)a[0] * (float)b[0] + (float)a[1] * (float)b[1];
#endif
}

__device__ __forceinline__ half2_t u2h2(uint u) {
    return __builtin_bit_cast(half2_t, u);
}

// --------- init: weights prep (blocks<448) + node embed (rest) ----------
__global__ __launch_bounds__(256)
void init_kernel(const float* __restrict__ x, const float* __restrict__ nW,
                 const float* __restrict__ nb_, const float* __restrict__ lin1,
                 const float* __restrict__ lin2, const float* __restrict__ proj,
                 uint* __restrict__ hb, ushort* __restrict__ wb,
                 float* __restrict__ projT)
{
    int bid = blockIdx.x;
    if (bid < 448) {
        int idx = bid * 256 + threadIdx.x;
        if (idx < 6 * HD * HD) {
            int m = idx >> 14, e = idx & (HD * HD - 1);
            const float* src = (m < 3) ? (lin1 + m * HD * HD) : (lin2 + (m - 3) * HD * HD);
            wb[idx] = (ushort)bfround(src[e]);
        } else if (idx < 7 * HD * HD) {
            int e = idx - 6 * HD * HD;
            int r = e >> 7, c = e & 127;
            projT[c * HD + r] = proj[r * HD + c];
        }
    } else {
        uint idx = (uint)(bid - 448) * 256u + threadIdx.x;
        uint node = idx >> 6, cp = idx & 63u;
        uint c2 = cp * 2u;
        const float* xr = x + node * NODE_F;
        const float* w0 = nW + c2 * NODE_F;
        const float* w1 = w0 + NODE_F;
        float a0 = nb_[c2], a1 = nb_[c2 + 1];
#pragma unroll
        for (int f = 0; f < NODE_F; ++f) { float xv = xr[f]; a0 += xv * w0[f]; a1 += xv * w1[f]; }
        hb[idx] = bfround(a0) | (bfround(a1) << 16);
    }
}

// ----------------------------- CSR construction ----------------------------
__global__ __launch_bounds__(256)
void hist_kernel(const int* __restrict__ ei, int* __restrict__ deg)
{
    int e = blockIdx.x * 256 + threadIdx.x;
    if (e < NE) atomicAdd(&deg[ei[NE + e]], 1);
}

__global__ __launch_bounds__(256)
void scan1_kernel(const int* __restrict__ deg, int* __restrict__ incl, int* __restrict__ bsum)
{
    int i = blockIdx.x * 256 + threadIdx.x;
    int v = (i < NN) ? deg[i] : 0;
    int lane = threadIdx.x & 63;
#pragma unroll
    for (int off = 1; off < 64; off <<= 1) {
        int u = __shfl_up(v, off);
        if (lane >= off) v += u;
    }
    __shared__ int wsum[4];
    if (lane == 63) wsum[threadIdx.x >> 6] = v;
    __syncthreads();
    int wid = threadIdx.x >> 6;
    int add = 0;
#pragma unroll
    for (int w = 0; w < 3; ++w) if (w < wid) add += wsum[w];
    v += add;
    if (i < NN) incl[i] = v;
    if (threadIdx.x == 255) bsum[blockIdx.x] = v;
}

__global__ __launch_bounds__(256)
void scan2_kernel(const int* __restrict__ bsum, int* __restrict__ bscan, int nb)
{
    int i = threadIdx.x;
    int v = (i < nb) ? bsum[i] : 0;
    int lane = i & 63;
#pragma unroll
    for (int off = 1; off < 64; off <<= 1) {
        int u = __shfl_up(v, off);
        if (lane >= off) v += u;
    }
    __shared__ int wsum[4];
    if (lane == 63) wsum[i >> 6] = v;
    __syncthreads();
    int wid = i >> 6;
    int add = 0;
#pragma unroll
    for (int w = 0; w < 3; ++w) if (w < wid) add += wsum[w];
    v += add;
    bscan[i] = v;
}

__global__ __launch_bounds__(256)
void scan3_kernel(const int* __restrict__ deg, const int* __restrict__ incl,
                  const int* __restrict__ bscan, int* __restrict__ row_start,
                  int* __restrict__ cursor)
{
    int i = blockIdx.x * 256 + threadIdx.x;
    if (i >= NN) return;
    int b = blockIdx.x;
    int base = (b > 0) ? bscan[b - 1] : 0;
    int rs = base + incl[i] - deg[i];
    row_start[i] = rs;
    cursor[i] = rs;
    if (i == 0) row_start[NN] = NE;
}

// ---- scatter + edge-feature pack: erec[pos] = {src, f16(ea[e])[0..6]} ----
// One 32-B random store per edge; ea read is sequential/coalesced.
__global__ __launch_bounds__(256)
void scatter_kernel(const int* __restrict__ ei, const float* __restrict__ ea,
                    int* __restrict__ cursor, uint* __restrict__ erec)
{
    int e = blockIdx.x * 256 + threadIdx.x;
    if (e >= NE) return;
    int s = ei[e], d = ei[NE + e];
    uint f[7];
    const float2* er = (const float2*)(ea + (size_t)e * EDGE_F);
#pragma unroll
    for (int i = 0; i < 7; ++i) {
        float2 v = er[i];
        half2_t hh;
        hh[0] = (_Float16)v.x;
        hh[1] = (_Float16)v.y;
        f[i] = __builtin_bit_cast(uint, hh);
    }
    int pos = atomicAdd(&cursor[d], 1);
    uint* dst = erec + (size_t)pos * 8;
    *(uint4*)dst = make_uint4((uint)s, f[0], f[1], f[2]);
    *(uint4*)(dst + 4) = make_uint4(f[3], f[4], f[5], f[6]);
}

// --- agg: zin_b[n] = bf16(hb[n] + sum_j relu(hb[rec.src] + f16dot(rec.f))) --
#define EMSGH(HV, EP)                                                       \
    {                                                                       \
        float ax = bx, ay = by;                                             \
        _Pragma("unroll")                                                   \
        for (int f = 0; f < 7; ++f) {                                       \
            half2_t av = u2h2((EP)[f]);                                     \
            ax = dot2f(av, w0h[f], ax);                                     \
            ay = dot2f(av, w1h[f], ay);                                     \
        }                                                                   \
        float hx = __uint_as_float((HV) << 16);                             \
        float hy = __uint_as_float((HV) & 0xffff0000u);                     \
        accx += fmaxf(hx + ax, 0.f);                                        \
        accy += fmaxf(hy + ay, 0.f);                                        \
    }

__global__ __launch_bounds__(256)
void agg_f16_kernel(const uint* __restrict__ hb, const uint* __restrict__ erec,
                    const int* __restrict__ row_start, const float* __restrict__ eW,
                    const float* __restrict__ eb, uint* __restrict__ zin_b)
{
    uint node = blockIdx.x * 4u + (threadIdx.x >> 6);
    if (node >= NN) return;
    uint lane = threadIdx.x & 63u;
    uint c2 = lane * 2u;
    const float4* wp = (const float4*)(eW + lane * 28u);
    float4 q0 = wp[0], q1 = wp[1], q2 = wp[2], q3 = wp[3], q4 = wp[4], q5 = wp[5], q6 = wp[6];
    half2_t w0h[7], w1h[7];
    w0h[0][0]=(_Float16)q0.x; w0h[0][1]=(_Float16)q0.y;
    w0h[1][0]=(_Float16)q0.z; w0h[1][1]=(_Float16)q0.w;
    w0h[2][0]=(_Float16)q1.x; w0h[2][1]=(_Float16)q1.y;
    w0h[3][0]=(_Float16)q1.z; w0h[3][1]=(_Float16)q1.w;
    w0h[4][0]=(_Float16)q2.x; w0h[4][1]=(_Float16)q2.y;
    w0h[5][0]=(_Float16)q2.z; w0h[5][1]=(_Float16)q2.w;
    w0h[6][0]=(_Float16)q3.x; w0h[6][1]=(_Float16)q3.y;
    w1h[0][0]=(_Float16)q3.z; w1h[0][1]=(_Float16)q3.w;
    w1h[1][0]=(_Float16)q4.x; w1h[1][1]=(_Float16)q4.y;
    w1h[2][0]=(_Float16)q4.z; w1h[2][1]=(_Float16)q4.w;
    w1h[3][0]=(_Float16)q5.x; w1h[3][1]=(_Float16)q5.y;
    w1h[4][0]=(_Float16)q5.z; w1h[4][1]=(_Float16)q5.w;
    w1h[5][0]=(_Float16)q6.x; w1h[5][1]=(_Float16)q6.y;
    w1h[6][0]=(_Float16)q6.z; w1h[6][1]=(_Float16)q6.w;
    float bx = eb[c2], by = eb[c2 + 1];
    float accx = 0.f, accy = 0.f;
    int beg = __builtin_amdgcn_readfirstlane(row_start[node]);
    int end = __builtin_amdgcn_readfirstlane(row_start[node + 1]);
    int j = beg;
    for (; j + 8 <= end; j += 8) {
        const uint* r0 = erec + (uint)j * 8u;
        uint s[8];
        uint hv[8];
#pragma unroll
        for (int q = 0; q < 8; ++q) s[q] = r0[q * 8];
#pragma unroll
        for (int q = 0; q < 8; ++q) hv[q] = hb[s[q] * 64u + lane];
        EMSGH(hv[0], r0 + 1);  EMSGH(hv[1], r0 + 9);
        EMSGH(hv[2], r0 + 17); EMSGH(hv[3], r0 + 25);
        EMSGH(hv[4], r0 + 33); EMSGH(hv[5], r0 + 41);
        EMSGH(hv[6], r0 + 49); EMSGH(hv[7], r0 + 57);
    }
    for (; j + 4 <= end; j += 4) {
        const uint* r0 = erec + (uint)j * 8u;
        uint s0 = r0[0], s1 = r0[8], s2 = r0[16], s3 = r0[24];
        uint hv0 = hb[s0 * 64u + lane];
        uint hv1 = hb[s1 * 64u + lane];
        uint hv2 = hb[s2 * 64u + lane];
        uint hv3 = hb[s3 * 64u + lane];
        EMSGH(hv0, r0 + 1);  EMSGH(hv1, r0 + 9);
        EMSGH(hv2, r0 + 17); EMSGH(hv3, r0 + 25);
    }
    for (; j < end; ++j) {
        const uint* r0 = erec + (uint)j * 8u;
        uint hv0 = hb[r0[0] * 64u + lane];
        EMSGH(hv0, r0 + 1);
    }
    uint hself = hb[node * 64u + lane];
    accx += __uint_as_float(hself << 16);
    accy += __uint_as_float(hself & 0xffff0000u);
    zin_b[node * 64u + lane] = bfround(accx) | (bfround(accy) << 16);
}

// --------- fused layer: hb = bf16(relu(relu(BN(zin@W1^T+b1))@W2^T+b2) + hb) --
__global__ __launch_bounds__(256)
void fused_layer_kernel(const uint* __restrict__ zin_b,
                        const ushort* __restrict__ w1b, const float* __restrict__ b1,
                        const float* __restrict__ gamma, const float* __restrict__ beta,
                        const float* __restrict__ mean, const float* __restrict__ var,
                        const ushort* __restrict__ w2b, const float* __restrict__ b2,
                        ushort* __restrict__ hb, int n)
{
    __shared__ uint Ahi[64 * 64];  // bf16[64][128], XOR-swizzled; reused for z
    const int t = threadIdx.x;
    const int nb = blockIdx.x * 64;

    {
        int row = t >> 2;
        int kq = (t & 3) * 16;
        int gn = nb + row;
        uint vals[16];
        if (gn < n) {
            const uint4* src = (const uint4*)(zin_b + (size_t)gn * 64 + kq);
#pragma unroll
            for (int i = 0; i < 4; ++i) {
                uint4 v = src[i];
                vals[4 * i] = v.x; vals[4 * i + 1] = v.y; vals[4 * i + 2] = v.z; vals[4 * i + 3] = v.w;
            }
        } else {
#pragma unroll
            for (int i = 0; i < 16; ++i) vals[i] = 0;
        }
        uint rowbase = row * 256;
#pragma unroll
        for (int i = 0; i < 4; ++i) {
            uint byte = (rowbase + (kq + 4 * i) * 4) ^ ((row & 7) << 4);
            *(uint4*)((char*)Ahi + byte) = make_uint4(vals[4 * i], vals[4 * i + 1], vals[4 * i + 2], vals[4 * i + 3]);
        }
    }

    const int w  = t >> 6, l = t & 63;
    const int lc = l & 15, lk = l >> 4;
    bf16x8 wf1[2][4], wf2[2][4];
#pragma unroll
    for (int ct = 0; ct < 2; ++ct)
#pragma unroll
        for (int ks = 0; ks < 4; ++ks) {
            size_t off = (size_t)(w * 32 + ct * 16 + lc) * HD + ks * 32 + lk * 8;
            wf1[ct][ks] = *(const bf16x8*)(w1b + off);
            wf2[ct][ks] = *(const bf16x8*)(w2b + off);
        }

    __syncthreads();

    f32x4 acc[4][2];
#pragma unroll
    for (int rt = 0; rt < 4; ++rt)
#pragma unroll
        for (int ct = 0; ct < 2; ++ct) acc[rt][ct] = (f32x4){0.f, 0.f, 0.f, 0.f};

#pragma unroll
    for (int ks = 0; ks < 4; ++ks) {
#pragma unroll
        for (int rt = 0; rt < 4; ++rt) {
            int row = rt * 16 + lc;
            uint byte = ((uint)(row * 256 + (ks * 32 + lk * 8) * 2)) ^ ((row & 7) << 4);
            bf16x8 ah = *(const bf16x8*)((char*)Ahi + byte);
            acc[rt][0] = __builtin_amdgcn_mfma_f32_16x16x32_bf16(ah, wf1[0][ks], acc[rt][0], 0, 0, 0);
            acc[rt][1] = __builtin_amdgcn_mfma_f32_16x16x32_bf16(ah, wf1[1][ks], acc[rt][1], 0, 0, 0);
        }
    }

    __syncthreads();

#pragma unroll
    for (int ct = 0; ct < 2; ++ct) {
        int col = w * 32 + ct * 16 + lc;
        float bi = b1[col];
        float scv = gamma[col] * rsqrtf(var[col] + BN_EPS);
        float shv = beta[col] - mean[col] * scv;
#pragma unroll
        for (int rt = 0; rt < 4; ++rt) {
#pragma unroll
            for (int r = 0; r < 4; ++r) {
                int rowl = rt * 16 + lk * 4 + r;
                float v = (acc[rt][ct][r] + bi) * scv + shv;
                v = fmaxf(v, 0.f);
                uint byte = ((uint)(rowl * 256 + col * 2)) ^ ((rowl & 7) << 4);
                *(ushort*)((char*)Ahi + byte) = (ushort)bfround(v);
            }
        }
    }

    __syncthreads();

    f32x4 acc2[4][2];
#pragma unroll
    for (int rt = 0; rt < 4; ++rt)
#pragma unroll
        for (int ct = 0; ct < 2; ++ct) acc2[rt][ct] = (f32x4){0.f, 0.f, 0.f, 0.f};

#pragma unroll
    for (int ks = 0; ks < 4; ++ks) {
#pragma unroll
        for (int rt = 0; rt < 4; ++rt) {
            int row = rt * 16 + lc;
            uint byte = ((uint)(row * 256 + (ks * 32 + lk * 8) * 2)) ^ ((row & 7) << 4);
            bf16x8 az = *(const bf16x8*)((char*)Ahi + byte);
            acc2[rt][0] = __builtin_amdgcn_mfma_f32_16x16x32_bf16(az, wf2[0][ks], acc2[rt][0], 0, 0, 0);
            acc2[rt][1] = __builtin_amdgcn_mfma_f32_16x16x32_bf16(az, wf2[1][ks], acc2[rt][1], 0, 0, 0);
        }
    }

#pragma unroll
    for (int ct = 0; ct < 2; ++ct) {
        int col = w * 32 + ct * 16 + lc;
        float bi = b2[col];
#pragma unroll
        for (int rt = 0; rt < 4; ++rt) {
#pragma unroll
            for (int r = 0; r < 4; ++r) {
                int row = nb + rt * 16 + lk * 4 + r;
                if (row < n) {
                    float hprev = __uint_as_float(((uint)hb[(size_t)row * HD + col]) << 16);
                    float v = fmaxf(acc2[rt][ct][r] + bi, 0.f) + hprev;
                    hb[(size_t)row * HD + col] = (ushort)bfround(v);
                }
            }
        }
    }
}

// -------- pooling over bf16 h: chunked local sums, rare atomics ----
__global__ __launch_bounds__(128)
void pool_kernel(const ushort* __restrict__ hb, const int* __restrict__ batch,
                 float* __restrict__ pooled, int* __restrict__ counts, int n, int chunk)
{
    int c = threadIdx.x;
    int n_start = blockIdx.x * chunk;
    if (n_start >= n) return;
    int n_end = min(n_start + chunk, n);
    float local = 0.f;
    int cnt = 0;
    int g_cur = batch[n_start];
    for (int nd = n_start; nd < n_end; ++nd) {
        int g = batch[nd];
        if (g != g_cur) {
            atomicAdd(&pooled[g_cur * HD + c], local);
            if (c == 0) atomicAdd(&counts[g_cur], cnt);
            local = 0.f; cnt = 0; g_cur = g;
        }
        local += __uint_as_float(((uint)hb[(size_t)nd * HD + c]) << 16);
        cnt++;
    }
    atomicAdd(&pooled[g_cur * HD + c], local);
    if (c == 0) atomicAdd(&counts[g_cur], cnt);
}

__global__ __launch_bounds__(128)
void final_kernel(const float* __restrict__ pooled, const int* __restrict__ counts,
                  const float* __restrict__ projT, const float* __restrict__ pb,
                  float* __restrict__ out)
{
    __shared__ float p_lds[HD];
    int g = blockIdx.x, p = threadIdx.x;
    float inv = 1.f / fmaxf((float)counts[g], 1.f);
    p_lds[p] = pooled[g * HD + p];
    __syncthreads();
    float acc = 0.f;
#pragma unroll 4
    for (int c = 0; c < HD; ++c) acc += p_lds[c] * projT[c * HD + p];
    out[g * HD + p] = acc * inv + pb[p];
}

extern "C" void kernel_launch(void* const* d_in, const int* in_sizes, int n_in,
                              void* d_out, int out_size, void* d_ws, size_t ws_size,
                              hipStream_t stream)
{
    const float* x        = (const float*)d_in[0];
    const int*   edge_idx = (const int*)d_in[1];
    const float* edge_attr= (const float*)d_in[2];
    const int*   batch    = (const int*)d_in[3];
    const float* node_W   = (const float*)d_in[4];
    const float* node_b   = (const float*)d_in[5];
    const float* edge_W   = (const float*)d_in[6];
    const float* edge_b   = (const float*)d_in[7];
    const float* lin1_b   = (const float*)d_in[9];
    const float* bn_gamma = (const float*)d_in[10];
    const float* bn_beta  = (const float*)d_in[11];
    const float* bn_mean  = (const float*)d_in[12];
    const float* bn_var   = (const float*)d_in[13];
    const float* lin2_b   = (const float*)d_in[15];
    const float* proj_b   = (const float*)d_in[17];

    char* ws = (char*)d_ws;
    uint*   hb       = (uint*)  (ws);                  // 12.8 MB (bf16 packed)
    uint*   zin_b    = (uint*)  (ws + 12800000);       // 12.8 MB (bf16 packed)
    uint*   erec     = (uint*)  (ws + 25600000);       // 25.6 MB  {src, f16ea[7]} x NE
    ushort* wb       = (ushort*)(ws + 51200000);       // 196,608
    float*  projT    = (float*) (ws + 51400000);       // 65,536
    float*  pooled   = (float*) (ws + 51500000);       // 32,768
    int*    counts   = (int*)   (ws + 51532768);       // 256
    int*    deg      = (int*)   (ws + 51540000);       // 200,000
    int*    incl     = (int*)   (ws + 51740000);       // 200,000
    int*    bsum     = (int*)   (ws + 51940000);       // 1,024
    int*    bscan    = (int*)   (ws + 51942048);       // 1,024
    int*    row_start= (int*)   (ws + 51944096);       // 200,064
    int*    cursor   = (int*)   (ws + 52144160);       // 200,000

    const int NB = (NN + 255) / 256;  // 196

    // --- CSR build + packed edge records (edge_index constant across layers) ---
    hipMemsetAsync(deg, 0, NN * sizeof(int), stream);
    hist_kernel<<<(NE + 255) / 256, 256, 0, stream>>>(edge_idx, deg);
    scan1_kernel<<<NB, 256, 0, stream>>>(deg, incl, bsum);
    scan2_kernel<<<1, 256, 0, stream>>>(bsum, bscan, NB);
    scan3_kernel<<<NB, 256, 0, stream>>>(deg, incl, bscan, row_start, cursor);
    scatter_kernel<<<(NE + 255) / 256, 256, 0, stream>>>(edge_idx, edge_attr, cursor, erec);

    // --- init: weights + node embed (hb) ---
    init_kernel<<<448 + 12500, 256, 0, stream>>>(
        x, node_W, node_b, (const float*)d_in[8], (const float*)d_in[14],
        (const float*)d_in[16], hb, wb, projT);

    for (int i = 0; i < NL; ++i) {
        agg_f16_kernel<<<(NN + 3) / 4, 256, 0, stream>>>(
            hb, erec, row_start, edge_W, edge_b, zin_b);
        fused_layer_kernel<<<(NN + 63) / 64, 256, 0, stream>>>(
            zin_b, wb + (size_t)i * HD * HD, lin1_b + i * HD,
            bn_gamma + i * HD, bn_beta + i * HD, bn_mean + i * HD, bn_var + i * HD,
            wb + (size_t)(3 + i) * HD * HD, lin2_b + i * HD,
            (ushort*)hb, NN);
    }

    hipMemsetAsync(pooled, 0, NG * HD * sizeof(float) + NG * sizeof(int) + 4000, stream);
    pool_kernel<<<(NN + 31) / 32, 128, 0, stream>>>((const ushort*)hb, batch, pooled, counts, NN, 32);
    final_kernel<<<NG, HD, 0, stream>>>(pooled, counts, projT, proj_b, (float*)d_out);
}

// Round 17
// 366.758 us; speedup vs baseline: 1.6905x; 1.0102x over previous
//
#include <hip/hip_runtime.h>

typedef unsigned int uint;
typedef unsigned short ushort;
typedef __attribute__((ext_vector_type(8))) short bf16x8;
typedef __attribute__((ext_vector_type(4))) float f32x4;
typedef __attribute__((ext_vector_type(2))) _Float16 half2_t;

#define NN 50000
#define NE 800000
#define NG 64
#define NODE_F 11
#define EDGE_F 14
#define HD 128
#define NL 3
#define BN_EPS 1e-5f

#if defined(__has_builtin)
#if __has_builtin(__builtin_amdgcn_fdot2)
#define HAS_DOT2 1
#endif
#endif

__device__ __forceinline__ uint bfround(float v) {
    uint b = __float_as_uint(v);
    return (b + 0x7fffu + ((b >> 16) & 1u)) >> 16;
}

__device__ __forceinline__ float dot2f(half2_t a, half2_t b, float acc) {
#ifdef HAS_DOT2
    return __builtin_amdgcn_fdot2(a, b, acc, false);
#else
    return acc + (float)a[0] * (float)b[0] + (float)a[1] * (float)b[1];
#endif
}

__device__ __forceinline__ half2_t u2h2(uint u) {
    return __builtin_bit_cast(half2_t, u);
}

// ----------------------------- CSR construction ----------------------------
__global__ __launch_bounds__(256)
void hist_kernel(const int* __restrict__ ei, int* __restrict__ deg)
{
    int e = blockIdx.x * 256 + threadIdx.x;
    if (e < NE) atomicAdd(&deg[ei[NE + e]], 1);
}

__global__ __launch_bounds__(256)
void scan1_kernel(const int* __restrict__ deg, int* __restrict__ incl, int* __restrict__ bsum)
{
    int i = blockIdx.x * 256 + threadIdx.x;
    int v = (i < NN) ? deg[i] : 0;
    int lane = threadIdx.x & 63;
#pragma unroll
    for (int off = 1; off < 64; off <<= 1) {
        int u = __shfl_up(v, off);
        if (lane >= off) v += u;
    }
    __shared__ int wsum[4];
    if (lane == 63) wsum[threadIdx.x >> 6] = v;
    __syncthreads();
    int wid = threadIdx.x >> 6;
    int add = 0;
#pragma unroll
    for (int w = 0; w < 3; ++w) if (w < wid) add += wsum[w];
    v += add;
    if (i < NN) incl[i] = v;
    if (threadIdx.x == 255) bsum[blockIdx.x] = v;
}

__global__ __launch_bounds__(256)
void scan2_kernel(const int* __restrict__ bsum, int* __restrict__ bscan, int nb)
{
    int i = threadIdx.x;
    int v = (i < nb) ? bsum[i] : 0;
    int lane = i & 63;
#pragma unroll
    for (int off = 1; off < 64; off <<= 1) {
        int u = __shfl_up(v, off);
        if (lane >= off) v += u;
    }
    __shared__ int wsum[4];
    if (lane == 63) wsum[i >> 6] = v;
    __syncthreads();
    int wid = i >> 6;
    int add = 0;
#pragma unroll
    for (int w = 0; w < 3; ++w) if (w < wid) add += wsum[w];
    v += add;
    bscan[i] = v;
}

__global__ __launch_bounds__(256)
void scan3_kernel(const int* __restrict__ deg, const int* __restrict__ incl,
                  const int* __restrict__ bscan, int* __restrict__ row_start,
                  int* __restrict__ cursor)
{
    int i = blockIdx.x * 256 + threadIdx.x;
    if (i >= NN) return;
    int b = blockIdx.x;
    int base = (b > 0) ? bscan[b - 1] : 0;
    int rs = base + incl[i] - deg[i];
    row_start[i] = rs;
    cursor[i] = rs;
    if (i == 0) row_start[NN] = NE;
}

// --- merged: scatter+pack (blocks<3125) | weights (3125..3572) | embed (rest)
// Scatter blocks launch first: latency/atomic-bound, init compute hides behind.
#define SC_BLKS 3125
#define W_BLKS  448
__global__ __launch_bounds__(256)
void scatter_init_kernel(const int* __restrict__ ei, const float* __restrict__ ea,
                         int* __restrict__ cursor, uint* __restrict__ erec,
                         const float* __restrict__ x, const float* __restrict__ nW,
                         const float* __restrict__ nb_, const float* __restrict__ lin1,
                         const float* __restrict__ lin2, const float* __restrict__ proj,
                         uint* __restrict__ hb, ushort* __restrict__ wb,
                         float* __restrict__ projT)
{
    int bid = blockIdx.x;
    if (bid < SC_BLKS) {
        int e = bid * 256 + threadIdx.x;
        if (e >= NE) return;
        int s = ei[e], d = ei[NE + e];
        uint f[7];
        const float2* er = (const float2*)(ea + (size_t)e * EDGE_F);
#pragma unroll
        for (int i = 0; i < 7; ++i) {
            float2 v = er[i];
            half2_t hh;
            hh[0] = (_Float16)v.x;
            hh[1] = (_Float16)v.y;
            f[i] = __builtin_bit_cast(uint, hh);
        }
        int pos = atomicAdd(&cursor[d], 1);
        uint* dst = erec + (size_t)pos * 8;
        *(uint4*)dst = make_uint4((uint)s, f[0], f[1], f[2]);
        *(uint4*)(dst + 4) = make_uint4(f[3], f[4], f[5], f[6]);
    } else if (bid < SC_BLKS + W_BLKS) {
        int idx = (bid - SC_BLKS) * 256 + threadIdx.x;
        if (idx < 6 * HD * HD) {
            int m = idx >> 14, e = idx & (HD * HD - 1);
            const float* src = (m < 3) ? (lin1 + m * HD * HD) : (lin2 + (m - 3) * HD * HD);
            wb[idx] = (ushort)bfround(src[e]);
        } else if (idx < 7 * HD * HD) {
            int e = idx - 6 * HD * HD;
            int r = e >> 7, c = e & 127;
            projT[c * HD + r] = proj[r * HD + c];
        }
    } else {
        uint idx = (uint)(bid - SC_BLKS - W_BLKS) * 256u + threadIdx.x;
        uint node = idx >> 6, cp = idx & 63u;
        uint c2 = cp * 2u;
        const float* xr = x + node * NODE_F;
        const float* w0 = nW + c2 * NODE_F;
        const float* w1 = w0 + NODE_F;
        float a0 = nb_[c2], a1 = nb_[c2 + 1];
#pragma unroll
        for (int f = 0; f < NODE_F; ++f) { float xv = xr[f]; a0 += xv * w0[f]; a1 += xv * w1[f]; }
        hb[idx] = bfround(a0) | (bfround(a1) << 16);
    }
}

// --- agg: zin_b[n] = bf16(hb[n] + sum_j relu(hb[rec.src] + f16dot(rec.f))) --
#define EMSGH(HV, EP)                                                       \
    {                                                                       \
        float ax = bx, ay = by;                                             \
        _Pragma("unroll")                                                   \
        for (int f = 0; f < 7; ++f) {                                       \
            half2_t av = u2h2((EP)[f]);                                     \
            ax = dot2f(av, w0h[f], ax);                                     \
            ay = dot2f(av, w1h[f], ay);                                     \
        }                                                                   \
        float hx = __uint_as_float((HV) << 16);                             \
        float hy = __uint_as_float((HV) & 0xffff0000u);                     \
        accx += fmaxf(hx + ax, 0.f);                                        \
        accy += fmaxf(hy + ay, 0.f);                                        \
    }

__global__ __launch_bounds__(256)
void agg_f16_kernel(const uint* __restrict__ hb, const uint* __restrict__ erec,
                    const int* __restrict__ row_start, const float* __restrict__ eW,
                    const float* __restrict__ eb, uint* __restrict__ zin_b)
{
    uint node = blockIdx.x * 4u + (threadIdx.x >> 6);
    if (node >= NN) return;
    uint lane = threadIdx.x & 63u;
    uint c2 = lane * 2u;
    const float4* wp = (const float4*)(eW + lane * 28u);
    float4 q0 = wp[0], q1 = wp[1], q2 = wp[2], q3 = wp[3], q4 = wp[4], q5 = wp[5], q6 = wp[6];
    half2_t w0h[7], w1h[7];
    w0h[0][0]=(_Float16)q0.x; w0h[0][1]=(_Float16)q0.y;
    w0h[1][0]=(_Float16)q0.z; w0h[1][1]=(_Float16)q0.w;
    w0h[2][0]=(_Float16)q1.x; w0h[2][1]=(_Float16)q1.y;
    w0h[3][0]=(_Float16)q1.z; w0h[3][1]=(_Float16)q1.w;
    w0h[4][0]=(_Float16)q2.x; w0h[4][1]=(_Float16)q2.y;
    w0h[5][0]=(_Float16)q2.z; w0h[5][1]=(_Float16)q2.w;
    w0h[6][0]=(_Float16)q3.x; w0h[6][1]=(_Float16)q3.y;
    w1h[0][0]=(_Float16)q3.z; w1h[0][1]=(_Float16)q3.w;
    w1h[1][0]=(_Float16)q4.x; w1h[1][1]=(_Float16)q4.y;
    w1h[2][0]=(_Float16)q4.z; w1h[2][1]=(_Float16)q4.w;
    w1h[3][0]=(_Float16)q5.x; w1h[3][1]=(_Float16)q5.y;
    w1h[4][0]=(_Float16)q5.z; w1h[4][1]=(_Float16)q5.w;
    w1h[5][0]=(_Float16)q6.x; w1h[5][1]=(_Float16)q6.y;
    w1h[6][0]=(_Float16)q6.z; w1h[6][1]=(_Float16)q6.w;
    float bx = eb[c2], by = eb[c2 + 1];
    float accx = 0.f, accy = 0.f;
    int beg = __builtin_amdgcn_readfirstlane(row_start[node]);
    int end = __builtin_amdgcn_readfirstlane(row_start[node + 1]);
    int j = beg;
    for (; j + 8 <= end; j += 8) {
        const uint* r0 = erec + (uint)j * 8u;
        uint s[8];
        uint hv[8];
#pragma unroll
        for (int q = 0; q < 8; ++q) s[q] = r0[q * 8];
#pragma unroll
        for (int q = 0; q < 8; ++q) hv[q] = hb[s[q] * 64u + lane];
        EMSGH(hv[0], r0 + 1);  EMSGH(hv[1], r0 + 9);
        EMSGH(hv[2], r0 + 17); EMSGH(hv[3], r0 + 25);
        EMSGH(hv[4], r0 + 33); EMSGH(hv[5], r0 + 41);
        EMSGH(hv[6], r0 + 49); EMSGH(hv[7], r0 + 57);
    }
    for (; j + 4 <= end; j += 4) {
        const uint* r0 = erec + (uint)j * 8u;
        uint s0 = r0[0], s1 = r0[8], s2 = r0[16], s3 = r0[24];
        uint hv0 = hb[s0 * 64u + lane];
        uint hv1 = hb[s1 * 64u + lane];
        uint hv2 = hb[s2 * 64u + lane];
        uint hv3 = hb[s3 * 64u + lane];
        EMSGH(hv0, r0 + 1);  EMSGH(hv1, r0 + 9);
        EMSGH(hv2, r0 + 17); EMSGH(hv3, r0 + 25);
    }
    for (; j < end; ++j) {
        const uint* r0 = erec + (uint)j * 8u;
        uint hv0 = hb[r0[0] * 64u + lane];
        EMSGH(hv0, r0 + 1);
    }
    uint hself = hb[node * 64u + lane];
    accx += __uint_as_float(hself << 16);
    accy += __uint_as_float(hself & 0xffff0000u);
    zin_b[node * 64u + lane] = bfround(accx) | (bfround(accy) << 16);
}

// --------- fused layer: hb = bf16(relu(relu(BN(zin@W1^T+b1))@W2^T+b2) + hb) --
__global__ __launch_bounds__(256)
void fused_layer_kernel(const uint* __restrict__ zin_b,
                        const ushort* __restrict__ w1b, const float* __restrict__ b1,
                        const float* __restrict__ gamma, const float* __restrict__ beta,
                        const float* __restrict__ mean, const float* __restrict__ var,
                        const ushort* __restrict__ w2b, const float* __restrict__ b2,
                        ushort* __restrict__ hb, int n)
{
    __shared__ uint Ahi[64 * 64];  // bf16[64][128], XOR-swizzled; reused for z
    const int t = threadIdx.x;
    const int nb = blockIdx.x * 64;

    {
        int row = t >> 2;
        int kq = (t & 3) * 16;
        int gn = nb + row;
        uint vals[16];
        if (gn < n) {
            const uint4* src = (const uint4*)(zin_b + (size_t)gn * 64 + kq);
#pragma unroll
            for (int i = 0; i < 4; ++i) {
                uint4 v = src[i];
                vals[4 * i] = v.x; vals[4 * i + 1] = v.y; vals[4 * i + 2] = v.z; vals[4 * i + 3] = v.w;
            }
        } else {
#pragma unroll
            for (int i = 0; i < 16; ++i) vals[i] = 0;
        }
        uint rowbase = row * 256;
#pragma unroll
        for (int i = 0; i < 4; ++i) {
            uint byte = (rowbase + (kq + 4 * i) * 4) ^ ((row & 7) << 4);
            *(uint4*)((char*)Ahi + byte) = make_uint4(vals[4 * i], vals[4 * i + 1], vals[4 * i + 2], vals[4 * i + 3]);
        }
    }

    const int w  = t >> 6, l = t & 63;
    const int lc = l & 15, lk = l >> 4;
    bf16x8 wf1[2][4], wf2[2][4];
#pragma unroll
    for (int ct = 0; ct < 2; ++ct)
#pragma unroll
        for (int ks = 0; ks < 4; ++ks) {
            size_t off = (size_t)(w * 32 + ct * 16 + lc) * HD + ks * 32 + lk * 8;
            wf1[ct][ks] = *(const bf16x8*)(w1b + off);
            wf2[ct][ks] = *(const bf16x8*)(w2b + off);
        }

    __syncthreads();

    f32x4 acc[4][2];
#pragma unroll
    for (int rt = 0; rt < 4; ++rt)
#pragma unroll
        for (int ct = 0; ct < 2; ++ct) acc[rt][ct] = (f32x4){0.f, 0.f, 0.f, 0.f};

#pragma unroll
    for (int ks = 0; ks < 4; ++ks) {
#pragma unroll
        for (int rt = 0; rt < 4; ++rt) {
            int row = rt * 16 + lc;
            uint byte = ((uint)(row * 256 + (ks * 32 + lk * 8) * 2)) ^ ((row & 7) << 4);
            bf16x8 ah = *(const bf16x8*)((char*)Ahi + byte);
            acc[rt][0] = __builtin_amdgcn_mfma_f32_16x16x32_bf16(ah, wf1[0][ks], acc[rt][0], 0, 0, 0);
            acc[rt][1] = __builtin_amdgcn_mfma_f32_16x16x32_bf16(ah, wf1[1][ks], acc[rt][1], 0, 0, 0);
        }
    }

    __syncthreads();

#pragma unroll
    for (int ct = 0; ct < 2; ++ct) {
        int col = w * 32 + ct * 16 + lc;
        float bi = b1[col];
        float scv = gamma[col] * rsqrtf(var[col] + BN_EPS);
        float shv = beta[col] - mean[col] * scv;
#pragma unroll
        for (int rt = 0; rt < 4; ++rt) {
#pragma unroll
            for (int r = 0; r < 4; ++r) {
                int rowl = rt * 16 + lk * 4 + r;
                float v = (acc[rt][ct][r] + bi) * scv + shv;
                v = fmaxf(v, 0.f);
                uint byte = ((uint)(rowl * 256 + col * 2)) ^ ((rowl & 7) << 4);
                *(ushort*)((char*)Ahi + byte) = (ushort)bfround(v);
            }
        }
    }

    __syncthreads();

    f32x4 acc2[4][2];
#pragma unroll
    for (int rt = 0; rt < 4; ++rt)
#pragma unroll
        for (int ct = 0; ct < 2; ++ct) acc2[rt][ct] = (f32x4){0.f, 0.f, 0.f, 0.f};

#pragma unroll
    for (int ks = 0; ks < 4; ++ks) {
#pragma unroll
        for (int rt = 0; rt < 4; ++rt) {
            int row = rt * 16 + lc;
            uint byte = ((uint)(row * 256 + (ks * 32 + lk * 8) * 2)) ^ ((row & 7) << 4);
            bf16x8 az = *(const bf16x8*)((char*)Ahi + byte);
            acc2[rt][0] = __builtin_amdgcn_mfma_f32_16x16x32_bf16(az, wf2[0][ks], acc2[rt][0], 0, 0, 0);
            acc2[rt][1] = __builtin_amdgcn_mfma_f32_16x16x32_bf16(az, wf2[1][ks], acc2[rt][1], 0, 0, 0);
        }
    }

#pragma unroll
    for (int ct = 0; ct < 2; ++ct) {
        int col = w * 32 + ct * 16 + lc;
        float bi = b2[col];
#pragma unroll
        for (int rt = 0; rt < 4; ++rt) {
#pragma unroll
            for (int r = 0; r < 4; ++r) {
                int row = nb + rt * 16 + lk * 4 + r;
                if (row < n) {
                    float hprev = __uint_as_float(((uint)hb[(size_t)row * HD + col]) << 16);
                    float v = fmaxf(acc2[rt][ct][r] + bi, 0.f) + hprev;
                    hb[(size_t)row * HD + col] = (ushort)bfround(v);
                }
            }
        }
    }
}

// -------- pooling over bf16 h: chunked local sums, rare atomics ----
__global__ __launch_bounds__(128)
void pool_kernel(const ushort* __restrict__ hb, const int* __restrict__ batch,
                 float* __restrict__ pooled, int* __restrict__ counts, int n, int chunk)
{
    int c = threadIdx.x;
    int n_start = blockIdx.x * chunk;
    if (n_start >= n) return;
    int n_end = min(n_start + chunk, n);
    float local = 0.f;
    int cnt = 0;
    int g_cur = batch[n_start];
    for (int nd = n_start; nd < n_end; ++nd) {
        int g = batch[nd];
        if (g != g_cur) {
            atomicAdd(&pooled[g_cur * HD + c], local);
            if (c == 0) atomicAdd(&counts[g_cur], cnt);
            local = 0.f; cnt = 0; g_cur = g;
        }
        local += __uint_as_float(((uint)hb[(size_t)nd * HD + c]) << 16);
        cnt++;
    }
    atomicAdd(&pooled[g_cur * HD + c], local);
    if (c == 0) atomicAdd(&counts[g_cur], cnt);
}

__global__ __launch_bounds__(128)
void final_kernel(const float* __restrict__ pooled, const int* __restrict__ counts,
                  const float* __restrict__ projT, const float* __restrict__ pb,
                  float* __restrict__ out)
{
    __shared__ float p_lds[HD];
    int g = blockIdx.x, p = threadIdx.x;
    float inv = 1.f / fmaxf((float)counts[g], 1.f);
    p_lds[p] = pooled[g * HD + p];
    __syncthreads();
    float acc = 0.f;
#pragma unroll 4
    for (int c = 0; c < HD; ++c) acc += p_lds[c] * projT[c * HD + p];
    out[g * HD + p] = acc * inv + pb[p];
}

extern "C" void kernel_launch(void* const* d_in, const int* in_sizes, int n_in,
                              void* d_out, int out_size, void* d_ws, size_t ws_size,
                              hipStream_t stream)
{
    const float* x        = (const float*)d_in[0];
    const int*   edge_idx = (const int*)d_in[1];
    const float* edge_attr= (const float*)d_in[2];
    const int*   batch    = (const int*)d_in[3];
    const float* node_W   = (const float*)d_in[4];
    const float* node_b   = (const float*)d_in[5];
    const float* edge_W   = (const float*)d_in[6];
    const float* edge_b   = (const float*)d_in[7];
    const float* lin1_b   = (const float*)d_in[9];
    const float* bn_gamma = (const float*)d_in[10];
    const float* bn_beta  = (const float*)d_in[11];
    const float* bn_mean  = (const float*)d_in[12];
    const float* bn_var   = (const float*)d_in[13];
    const float* lin2_b   = (const float*)d_in[15];
    const float* proj_b   = (const float*)d_in[17];

    char* ws = (char*)d_ws;
    uint*   hb       = (uint*)  (ws);                  // 12.8 MB (bf16 packed)
    uint*   zin_b    = (uint*)  (ws + 12800000);       // 12.8 MB (bf16 packed)
    uint*   erec     = (uint*)  (ws + 25600000);       // 25.6 MB  {src, f16ea[7]} x NE
    ushort* wb       = (ushort*)(ws + 51200000);       // 196,608
    float*  projT    = (float*) (ws + 51400000);       // 65,536
    float*  pooled   = (float*) (ws + 51500000);       // 32,768
    int*    counts   = (int*)   (ws + 51532768);       // 256
    int*    deg      = (int*)   (ws + 51540000);       // 200,000
    int*    incl     = (int*)   (ws + 51740000);       // 200,000
    int*    bsum     = (int*)   (ws + 51940000);       // 1,024
    int*    bscan    = (int*)   (ws + 51942048);       // 1,024
    int*    row_start= (int*)   (ws + 51944096);       // 200,064
    int*    cursor   = (int*)   (ws + 52144160);       // 200,000

    const int NB = (NN + 255) / 256;  // 196

    // --- CSR build ---
    hipMemsetAsync(deg, 0, NN * sizeof(int), stream);
    hist_kernel<<<(NE + 255) / 256, 256, 0, stream>>>(edge_idx, deg);
    scan1_kernel<<<NB, 256, 0, stream>>>(deg, incl, bsum);
    scan2_kernel<<<1, 256, 0, stream>>>(bsum, bscan, NB);
    scan3_kernel<<<NB, 256, 0, stream>>>(deg, incl, bscan, row_start, cursor);

    // --- merged scatter+pack | weights | node embed ---
    scatter_init_kernel<<<SC_BLKS + W_BLKS + 12500, 256, 0, stream>>>(
        edge_idx, edge_attr, cursor, erec,
        x, node_W, node_b, (const float*)d_in[8], (const float*)d_in[14],
        (const float*)d_in[16], hb, wb, projT);

    for (int i = 0; i < NL; ++i) {
        agg_f16_kernel<<<(NN + 3) / 4, 256, 0, stream>>>(
            hb, erec, row_start, edge_W, edge_b, zin_b);
        fused_layer_kernel<<<(NN + 63) / 64, 256, 0, stream>>>(
            zin_b, wb + (size_t)i * HD * HD, lin1_b + i * HD,
            bn_gamma + i * HD, bn_beta + i * HD, bn_mean + i * HD, bn_var + i * HD,
            wb + (size_t)(3 + i) * HD * HD, lin2_b + i * HD,
            (ushort*)hb, NN);
    }

    hipMemsetAsync(pooled, 0, NG * HD * sizeof(float) + NG * sizeof(int) + 4000, stream);
    pool_kernel<<<(NN + 31) / 32, 128, 0, stream>>>((const ushort*)hb, batch, pooled, counts, NN, 32);
    final_kernel<<<NG, HD, 0, stream>>>(pooled, counts, projT, proj_b, (float*)d_out);
}